// Round 4
// baseline (308.527 us; speedup 1.0000x reference)
//
#include <hip/hip_runtime.h>

#define N_NODES 50000
#define N_EDGES 800000
#define E_TOT   850000   /* N_EDGES + N_NODES self-loops */
#define C_IN    512
#define C_HID   128
#define NEG     0.2f

typedef _Float16 f16x8 __attribute__((ext_vector_type(8)));
typedef __attribute__((ext_vector_type(4))) float f32x4;

__device__ __forceinline__ float leaky(float x) { return x > 0.f ? x : NEG * x; }

union U32H2 { unsigned u; _Float16 h[2]; float f; };
union BFrag { uint4 u; f16x8 h; };
union AFrag { unsigned u[4]; f16x8 h; };

__device__ __forceinline__ unsigned short f2h(float f) {
  U32H2 c; c.h[0] = (_Float16)f; return (unsigned short)(c.u & 0xffff);
}

// pack two fp32 -> fp16x2 (RTZ hardware op) as raw u32
__device__ __forceinline__ unsigned pk2h(float a, float b) {
  union { __fp16 v __attribute__((ext_vector_type(2))); unsigned u; } c;
  c.v = __builtin_amdgcn_cvt_pkrtz(a, b);
  return c.u;
}

// Full 16-lane (DPP row) all-reduce add on the VALU pipe — zero DS ops.
// Stages: quad xor1, quad xor2, row_ror:4, row_ror:8.
__device__ __forceinline__ float row_reduce_add(float v) {
  union { float f; int i; } a, b;
  a.f = v;
  b.i = __builtin_amdgcn_update_dpp(0, a.i, 0xB1, 0xF, 0xF, true);  a.f += b.f;
  b.i = __builtin_amdgcn_update_dpp(0, a.i, 0x4E, 0xF, 0xF, true);  a.f += b.f;
  b.i = __builtin_amdgcn_update_dpp(0, a.i, 0x124, 0xF, 0xF, true); a.f += b.f;
  b.i = __builtin_amdgcn_update_dpp(0, a.i, 0x128, 0xF, 0xF, true); a.f += b.f;
  return a.f;
}

// ---------------------------------------------------------------------------
// setup: fuses prep_w (blocks 0..31), prep_v (32..159), deg+rank (160..3284).
// ---------------------------------------------------------------------------
__global__ __launch_bounds__(256) void setup_kernel(
    const float* __restrict__ W1, const float* __restrict__ as1,
    const float* __restrict__ ad1, const int* __restrict__ ei,
    unsigned short* __restrict__ Wswz, float* __restrict__ v1s, float* __restrict__ v1d,
    int* __restrict__ deg, int* __restrict__ rnk) {
  const int b = blockIdx.x;
  if (b < 32) {
    int t = b * 256 + threadIdx.x;                 // 8192 threads
    int c = t >> 6, kc = t & 63;
    if (c >= C_HID) return;
    int kblk = kc >> 2, q = kc & 3;
    int ct = c >> 4, l15 = c & 15;
    int lane = q * 16 + l15;
    unsigned short hb[8], lb[8];
#pragma unroll
    for (int i = 0; i < 8; i++) {
      float w = W1[(size_t)(kc * 8 + i) * C_HID + c];
      _Float16 hi = (_Float16)w;                   // RNE
      _Float16 lo = (_Float16)(w - (float)hi);
      U32H2 ch; ch.h[0] = hi;
      U32H2 cl; cl.h[0] = lo;
      hb[i] = (unsigned short)(ch.u & 0xffff);
      lb[i] = (unsigned short)(cl.u & 0xffff);
    }
    size_t chunk0 = ((size_t)(kblk * 8 + ct) * 2) * 512;
    *(uint4*)&Wswz[chunk0 + (size_t)lane * 8]       = *(uint4*)hb;
    *(uint4*)&Wswz[chunk0 + 512 + (size_t)lane * 8] = *(uint4*)lb;
  } else if (b < 160) {
    const int wv = threadIdx.x >> 6, lane = threadIdx.x & 63;
    const int k = (b - 32) * 4 + wv;
    if (k >= C_IN) return;
    float2 w = *(const float2*)(W1 + (size_t)k * C_HID + 2 * lane);
    float2 a = *(const float2*)(as1 + 2 * lane);
    float2 d = *(const float2*)(ad1 + 2 * lane);
    float s = w.x * a.x + w.y * a.y;
    float t = w.x * d.x + w.y * d.y;
#pragma unroll
    for (int m = 32; m >= 1; m >>= 1) {
      s += __shfl_xor(s, m, 64);
      t += __shfl_xor(t, m, 64);
    }
    if (lane == 0) { v1s[k] = s; v1d[k] = t; }
  } else {
    int e = (b - 160) * 256 + threadIdx.x;
    if (e < N_EDGES) rnk[e] = atomicAdd(&deg[ei[N_EDGES + e]], 1);
  }
}

// ---------------------------------------------------------------------------
// lin1: h1 = x @ W1 via fp16 MFMA (x_h*W_hi + x_h*W_lo), fused fp32 a_src/a_dst.
// ZERO LDS / ZERO barriers for the GEMM: the mfma_16x16x32 A-fragment (lane =
// row l&15, k-chunk (l>>4)*8) is 8 CONTIGUOUS floats of one x row, so each
// lane loads its fragment straight from global (one 128-B line per row per
// kblk), converts with pk2h, and feeds MFMA. Each wave independently owns a
// 32-row x 64-col tile (block = 64 rows x 128 cols); B (Wswz) is L2-resident.
// All 16 k-iterations are independent -> deep compiler pipelining; next-iter
// A prefetch hides HBM latency. Block 0 runs the rowptr scan (hidden).
// ---------------------------------------------------------------------------
__global__ __launch_bounds__(256) void lin1_kernel(const float* __restrict__ x,
    const unsigned short* __restrict__ Wswz,
    const float* __restrict__ v1s, const float* __restrict__ v1d,
    unsigned short* __restrict__ h1u, float* __restrict__ a_src, float* __restrict__ a_dst,
    const int* __restrict__ deg, int* __restrict__ rowptr) {
  __shared__ int wsum[4];

  if (blockIdx.x == 0) {
    // ---- scan block: exclusive prefix of (deg+1) over 50000 nodes ----
    const int tid = threadIdx.x, lane = tid & 63, wv = tid >> 6;
    int carry = 0;
    for (int base = 0; base < N_NODES; base += 8192) {
      int i0 = base + tid * 32;
      int v[32];
      if (i0 + 32 <= N_NODES) {
#pragma unroll
        for (int k = 0; k < 8; k++) {
          int4 t4 = *(const int4*)(deg + i0 + 4 * k);
          v[4 * k]     = t4.x + 1; v[4 * k + 1] = t4.y + 1;
          v[4 * k + 2] = t4.z + 1; v[4 * k + 3] = t4.w + 1;
        }
      } else {
#pragma unroll
        for (int k = 0; k < 32; k++) v[k] = (i0 + k < N_NODES) ? deg[i0 + k] + 1 : 0;
      }
      int tsum = 0;
#pragma unroll
      for (int k = 0; k < 32; k++) tsum += v[k];
      int sc = tsum;                                   // inclusive scan of thread sums
#pragma unroll
      for (int off = 1; off < 64; off <<= 1) {
        int t = __shfl_up(sc, off, 64);
        if (lane >= off) sc += t;
      }
      if (lane == 63) wsum[wv] = sc;
      __syncthreads();
      if (tid < 4) {
        int s = wsum[tid];
#pragma unroll
        for (int off = 1; off < 4; off <<= 1) {
          int t = __shfl_up(s, off, 64);
          if (tid >= off) s += t;
        }
        wsum[tid] = s;
      }
      __syncthreads();
      int run = carry + (wv ? wsum[wv - 1] : 0) + sc - tsum;   // exclusive base
      if (i0 + 32 <= N_NODES) {
#pragma unroll
        for (int k = 0; k < 8; k++) {
          int4 w4;
          w4.x = run; run += v[4 * k];
          w4.y = run; run += v[4 * k + 1];
          w4.z = run; run += v[4 * k + 2];
          w4.w = run; run += v[4 * k + 3];
          *(int4*)(rowptr + i0 + 4 * k) = w4;
        }
      } else {
#pragma unroll
        for (int k = 0; k < 32; k++) {
          if (i0 + k < N_NODES) rowptr[i0 + k] = run;
          run += v[k];
        }
      }
      carry += wsum[3];
      __syncthreads();
    }
    if (tid == 0) rowptr[N_NODES] = carry;
    return;
  }

  const int tid  = threadIdx.x;
  const int lane = tid & 63, wv = tid >> 6;
  const int wr = wv >> 1, wc = wv & 1;            // wave's row-half / col-half
  const int q = lane >> 4, r15 = lane & 15;
  const int m0 = (blockIdx.x - 1) * 64;

  const int row0 = m0 + wr * 32 + r15;            // rt=0 row owned by this lane
  const int row1 = row0 + 16;                     // rt=1 row
  const int lr0 = min(row0, N_NODES - 1);         // clamp loads; stores guarded
  const int lr1 = min(row1, N_NODES - 1);
  const float* xr0 = x + (size_t)lr0 * C_IN + q * 8;
  const float* xr1 = x + (size_t)lr1 * C_IN + q * 8;
  const float* vsp = v1s + q * 8;
  const float* vdp = v1d + q * 8;

  f32x4 acc[2][4];
#pragma unroll
  for (int rt = 0; rt < 2; rt++)
#pragma unroll
    for (int ct = 0; ct < 4; ct++) acc[rt][ct] = (f32x4)0.f;
  float ps0 = 0.f, pd0 = 0.f, ps1 = 0.f, pd1 = 0.f;

  // prefetch A for kblk 0
  float4 a0a = *(const float4*)(xr0);
  float4 a0b = *(const float4*)(xr0 + 4);
  float4 a1a = *(const float4*)(xr1);
  float4 a1b = *(const float4*)(xr1 + 4);

#pragma unroll
  for (int kblk = 0; kblk < 16; kblk++) {
    const int k0 = kblk * 32;
    // attention dot partials (fp32) — same per-lane accumulation pattern and
    // order as the LDS version (bit-identical results)
    float4 vsa = *(const float4*)(vsp + k0);
    float4 vsb = *(const float4*)(vsp + k0 + 4);
    float4 vda = *(const float4*)(vdp + k0);
    float4 vdb = *(const float4*)(vdp + k0 + 4);
    ps0 += a0a.x * vsa.x + a0a.y * vsa.y + a0a.z * vsa.z + a0a.w * vsa.w
         + a0b.x * vsb.x + a0b.y * vsb.y + a0b.z * vsb.z + a0b.w * vsb.w;
    pd0 += a0a.x * vda.x + a0a.y * vda.y + a0a.z * vda.z + a0a.w * vda.w
         + a0b.x * vdb.x + a0b.y * vdb.y + a0b.z * vdb.z + a0b.w * vdb.w;
    ps1 += a1a.x * vsa.x + a1a.y * vsa.y + a1a.z * vsa.z + a1a.w * vsa.w
         + a1b.x * vsb.x + a1b.y * vsb.y + a1b.z * vsb.z + a1b.w * vsb.w;
    pd1 += a1a.x * vda.x + a1a.y * vda.y + a1a.z * vda.z + a1a.w * vda.w
         + a1b.x * vdb.x + a1b.y * vdb.y + a1b.z * vdb.z + a1b.w * vdb.w;

    AFrag af0, af1;                               // A fragments (RTZ pack, as before)
    af0.u[0] = pk2h(a0a.x, a0a.y); af0.u[1] = pk2h(a0a.z, a0a.w);
    af0.u[2] = pk2h(a0b.x, a0b.y); af0.u[3] = pk2h(a0b.z, a0b.w);
    af1.u[0] = pk2h(a1a.x, a1a.y); af1.u[1] = pk2h(a1a.z, a1a.w);
    af1.u[2] = pk2h(a1b.x, a1b.y); af1.u[3] = pk2h(a1b.z, a1b.w);

    if (kblk < 15) {                              // prefetch next A chunk
      a0a = *(const float4*)(xr0 + k0 + 32);
      a0b = *(const float4*)(xr0 + k0 + 36);
      a1a = *(const float4*)(xr1 + k0 + 32);
      a1b = *(const float4*)(xr1 + k0 + 36);
    }

    // B fragments: 4 col-tiles (this wave's col-half), hi+lo each, L2-hot
    const unsigned short* bp = Wswz + (size_t)(kblk * 8 + wc * 4) * 1024 + (size_t)lane * 8;
#pragma unroll
    for (int ct = 0; ct < 4; ct++) {
      BFrag bh, bl;
      bh.u = *(const uint4*)(bp + ct * 1024);
      bl.u = *(const uint4*)(bp + ct * 1024 + 512);
      acc[0][ct] = __builtin_amdgcn_mfma_f32_16x16x32_f16(af0.h, bh.h, acc[0][ct], 0, 0, 0);
      acc[0][ct] = __builtin_amdgcn_mfma_f32_16x16x32_f16(af0.h, bl.h, acc[0][ct], 0, 0, 0);
      acc[1][ct] = __builtin_amdgcn_mfma_f32_16x16x32_f16(af1.h, bh.h, acc[1][ct], 0, 0, 0);
      acc[1][ct] = __builtin_amdgcn_mfma_f32_16x16x32_f16(af1.h, bl.h, acc[1][ct], 0, 0, 0);
    }
  }

  // attention dots: fold the 4 k-chunk lanes (lane bits 4,5); same tree shape
  ps0 += __shfl_xor(ps0, 16, 64); ps0 += __shfl_xor(ps0, 32, 64);
  pd0 += __shfl_xor(pd0, 16, 64); pd0 += __shfl_xor(pd0, 32, 64);
  ps1 += __shfl_xor(ps1, 16, 64); ps1 += __shfl_xor(ps1, 32, 64);
  pd1 += __shfl_xor(pd1, 16, 64); pd1 += __shfl_xor(pd1, 32, 64);
  if (q == 0) {
    if (row0 < N_NODES) { a_src[row0] = ps0; a_dst[row0] = pd0; }
    if (row1 < N_NODES) { a_src[row1] = ps1; a_dst[row1] = pd1; }
  }

  // C store (fp16): C/D layout col=lane&15, row=(lane>>4)*4+reg
#pragma unroll
  for (int rt = 0; rt < 2; rt++) {
    int rbase = m0 + wr * 32 + rt * 16 + q * 4;
#pragma unroll
    for (int ct = 0; ct < 4; ct++) {
      int col = wc * 64 + ct * 16 + r15;
#pragma unroll
      for (int ri = 0; ri < 4; ri++) {
        int row = rbase + ri;
        if (row < N_NODES)
          h1u[(size_t)row * C_HID + col] = f2h(acc[rt][ct][ri]);
      }
    }
  }
}

// ---------------------------------------------------------------------------
// bucket: no atomics. Edge e -> slot rowptr[dst]+rank[e]; self-loop n -> slot
// rowptr[n+1]-1. Weight w = exp(leaky(a_src+a_dst)) fused in.
// ---------------------------------------------------------------------------
__global__ void bucket_kernel(const int* __restrict__ ei, const int* __restrict__ rnk,
                              const int* __restrict__ rowptr,
                              const float* __restrict__ a_src, const float* __restrict__ a_dst,
                              int2* __restrict__ esw) {
  int e = blockIdx.x * blockDim.x + threadIdx.x;
  if (e >= E_TOT) return;
  int src, slot;
  if (e < N_EDGES) {
    src = ei[e];
    int dst = ei[N_EDGES + e];
    slot = rowptr[dst] + rnk[e];
    U32H2 c; c.f = __expf(leaky(a_src[src] + a_dst[dst]));
    esw[slot] = make_int2(src, (int)c.u);
  } else {
    int n = e - N_EDGES;
    slot = rowptr[n + 1] - 1;
    U32H2 c; c.f = __expf(leaky(a_src[n] + a_dst[n]));
    esw[slot] = make_int2(n, (int)c.u);
  }
}

// ---------------------------------------------------------------------------
// agg1: 16 lanes per node (4 nodes/wave), lane r owns channels r*8..r*8+7.
// ZERO DS ops: edge records read via same-address broadcast loads (L1-hot
// bucket lines) so every lane sees every (s,w) -> no s/w shuffles, no acc
// fold, and wsum needs no reduction. Per 8-edge round: 8 record loads + 8
// independent 16-B gathers in flight per lane. Padded slots clamp to the
// bucket's first record (one hot line) with w=0. Epilogue p-fold uses DPP
// row reduction (VALU pipe). hs2[n] = {p0..p5, as0..as2, ad0..ad2}.
// ---------------------------------------------------------------------------
__global__ __launch_bounds__(256) void agg1_kernel(const unsigned short* __restrict__ h1u,
    const int2* __restrict__ esw, const int* __restrict__ rowptr,
    const float* __restrict__ bias1, const float* __restrict__ W2,
    const float* __restrict__ as2w, const float* __restrict__ ad2w,
    float* __restrict__ hs2) {
  const int wv = threadIdx.x >> 6, lane = threadIdx.x & 63;
  const int r = lane & 15;
  const int n = blockIdx.x * 16 + wv * 4 + (lane >> 4);   // grid covers N exactly
  const int start = rowptr[n], end = rowptr[n + 1];

  const unsigned short* hbase = h1u + r * 8;

  float acc[8] = {0, 0, 0, 0, 0, 0, 0, 0};
  float wsum = 0.f;
  for (int base = start; base < end; base += 8) {
    const int cnt = end - base;                    // group-uniform
    int2 rec[8];
#pragma unroll
    for (int j = 0; j < 8; j++)
      rec[j] = esw[j < cnt ? base + j : base];     // clamp: bucket's first record
    uint4 g[8];
#pragma unroll
    for (int j = 0; j < 8; j++)
      g[j] = *(const uint4*)(hbase + (size_t)rec[j].x * C_HID);
#pragma unroll
    for (int j = 0; j < 8; j++) {
      U32H2 cw; cw.u = (unsigned)rec[j].y;
      const float W = (j < cnt) ? cw.f : 0.f;
      wsum += W;
      U32H2 c0, c1, c2, c3;
      c0.u = g[j].x; c1.u = g[j].y; c2.u = g[j].z; c3.u = g[j].w;
      acc[0] = fmaf(W, (float)c0.h[0], acc[0]); acc[1] = fmaf(W, (float)c0.h[1], acc[1]);
      acc[2] = fmaf(W, (float)c1.h[0], acc[2]); acc[3] = fmaf(W, (float)c1.h[1], acc[3]);
      acc[4] = fmaf(W, (float)c2.h[0], acc[4]); acc[5] = fmaf(W, (float)c2.h[1], acc[5]);
      acc[6] = fmaf(W, (float)c3.h[0], acc[6]); acc[7] = fmaf(W, (float)c3.h[1], acc[7]);
    }
  }

  const float inv = 1.f / wsum;                    // > 0 via self-loop; uniform in group

  float4 ba = *(const float4*)(bias1 + r * 8);
  float4 bb = *(const float4*)(bias1 + r * 8 + 4);
  float u[8] = {fmaxf(acc[0] * inv + ba.x, 0.f), fmaxf(acc[1] * inv + ba.y, 0.f),
                fmaxf(acc[2] * inv + ba.z, 0.f), fmaxf(acc[3] * inv + ba.w, 0.f),
                fmaxf(acc[4] * inv + bb.x, 0.f), fmaxf(acc[5] * inv + bb.y, 0.f),
                fmaxf(acc[6] * inv + bb.z, 0.f), fmaxf(acc[7] * inv + bb.w, 0.f)};
  float p[6] = {0, 0, 0, 0, 0, 0};
#pragma unroll
  for (int j = 0; j < 8; j++) {
    const float* w2r = W2 + (size_t)(r * 8 + j) * 6;   // L1-hot (3 KB total)
#pragma unroll
    for (int o = 0; o < 6; o++) p[o] = fmaf(u[j], w2r[o], p[o]);
  }
  // fold over the 16 lanes of the group — DPP, zero DS ops
#pragma unroll
  for (int o = 0; o < 6; o++) p[o] = row_reduce_add(p[o]);

  if (r == 0) {
    float as0 = p[0] * as2w[0] + p[1] * as2w[1];
    float as1 = p[2] * as2w[2] + p[3] * as2w[3];
    float as2_ = p[4] * as2w[4] + p[5] * as2w[5];
    float ad0 = p[0] * ad2w[0] + p[1] * ad2w[1];
    float ad1 = p[2] * ad2w[2] + p[3] * ad2w[3];
    float ad2_ = p[4] * ad2w[4] + p[5] * ad2w[5];
    float* dst = hs2 + (size_t)n * 12;
    *(float4*)(dst)     = make_float4(p[0], p[1], p[2], p[3]);
    *(float4*)(dst + 4) = make_float4(p[4], p[5], as0, as1);
    *(float4*)(dst + 8) = make_float4(as2_, ad0, ad1, ad2_);
  }
}

// ---------------------------------------------------------------------------
// agg2: 16 lanes per node (4 nodes/wave); per edge ONE 48-B packed record
// {p0..p5, as0..as2} (3 loads, 1-2 lines). Folds via DPP row reduction.
// out = mean over heads + bias2.
// ---------------------------------------------------------------------------
__global__ __launch_bounds__(256) void agg2_kernel(const float* __restrict__ hs2,
    const int* __restrict__ rowptr, const int2* __restrict__ esw,
    const float* __restrict__ bias2, float* __restrict__ out) {
  const int wv = threadIdx.x >> 6, lane = threadIdx.x & 63;
  const int q = lane >> 4, r = lane & 15;
  const int n = blockIdx.x * 16 + wv * 4 + q;
  if (n >= N_NODES) return;
  const int start = rowptr[n], end = rowptr[n + 1];
  float4 own = *(const float4*)(hs2 + (size_t)n * 12 + 8);   // {as2, ad0, ad1, ad2}
  const float ad0 = own.y, ad1 = own.z, ad2 = own.w;

  float d0 = 0.f, d1 = 0.f, d2 = 0.f;
  float a0 = 0.f, a1 = 0.f, a2 = 0.f, a3 = 0.f, a4 = 0.f, a5 = 0.f;
  for (int j = start + r; j < end; j += 16) {
    int s = esw[j].x;
    const float* rec = hs2 + (size_t)s * 12;
    float4 A = *(const float4*)(rec);          // p0..p3
    float4 B = *(const float4*)(rec + 4);      // p4, p5, as0, as1
    float  C = rec[8];                         // as2
    float e0 = __expf(leaky(B.z + ad0));
    float e1 = __expf(leaky(B.w + ad1));
    float e2 = __expf(leaky(C + ad2));
    d0 += e0; d1 += e1; d2 += e2;
    a0 += e0 * A.x; a1 += e0 * A.y;
    a2 += e1 * A.z; a3 += e1 * A.w;
    a4 += e2 * B.x; a5 += e2 * B.y;
  }
  d0 = row_reduce_add(d0); d1 = row_reduce_add(d1); d2 = row_reduce_add(d2);
  a0 = row_reduce_add(a0); a1 = row_reduce_add(a1); a2 = row_reduce_add(a2);
  a3 = row_reduce_add(a3); a4 = row_reduce_add(a4); a5 = row_reduce_add(a5);
  if (r == 0) {
    float o0 = (a0 / d0 + a2 / d1 + a4 / d2) * (1.f / 3.f) + bias2[0];
    float o1 = (a1 / d0 + a3 / d1 + a5 / d2) * (1.f / 3.f) + bias2[1];
    *(float2*)(out + (size_t)n * 2) = make_float2(o0, o1);
  }
}

// ---------------------------------------------------------------------------
extern "C" void kernel_launch(void* const* d_in, const int* in_sizes, int n_in,
                              void* d_out, int out_size, void* d_ws, size_t ws_size,
                              hipStream_t stream) {
  const float* x        = (const float*)d_in[0];
  const int*   ei       = (const int*)d_in[1];
  const float* W1       = (const float*)d_in[2];
  const float* att_src1 = (const float*)d_in[3];
  const float* att_dst1 = (const float*)d_in[4];
  const float* bias1    = (const float*)d_in[5];
  const float* W2       = (const float*)d_in[6];
  const float* att_src2 = (const float*)d_in[7];
  const float* att_dst2 = (const float*)d_in[8];
  const float* bias2    = (const float*)d_in[9];
  float* out = (float*)d_out;

  char* w = (char*)d_ws;
  auto alloc = [&](size_t bytes) {
    char* p = w;
    w += (bytes + 255) & ~(size_t)255;
    return p;
  };
  unsigned short* h1u    = (unsigned short*)alloc((size_t)N_NODES * C_HID * 2);  // 12.8 MB
  unsigned short* Wswz   = (unsigned short*)alloc((size_t)C_IN * C_HID * 2 * 2); // 256 KB
  float*          v1s    = (float*)alloc((size_t)C_IN * 4);
  float*          v1d    = (float*)alloc((size_t)C_IN * 4);
  float*          a_src1 = (float*)alloc((size_t)N_NODES * 4);
  float*          a_dst1 = (float*)alloc((size_t)N_NODES * 4);
  int*            deg    = (int*)alloc((size_t)N_NODES * 4);
  int*            rowptr = (int*)alloc((size_t)(N_NODES + 4) * 4);
  int*            rnk    = (int*)alloc((size_t)N_EDGES * 4);                     // 3.2 MB
  int2*           esw    = (int2*)alloc((size_t)E_TOT * 8);                      // 6.8 MB
  float*          hs2    = (float*)alloc((size_t)N_NODES * 12 * 4);              // 2.4 MB

  (void)hipMemsetAsync(deg, 0, (size_t)N_NODES * 4, stream);

  setup_kernel<<<160 + (N_EDGES + 255) / 256, 256, 0, stream>>>(
      W1, att_src1, att_dst1, ei, Wswz, v1s, v1d, deg, rnk);
  // scan folded into lin1's block 0 (runs concurrent with the GEMM blocks)
  lin1_kernel<<<(N_NODES + 63) / 64 + 1, 256, 0, stream>>>(x, Wswz, v1s, v1d,
                                                           h1u, a_src1, a_dst1,
                                                           deg, rowptr);
  bucket_kernel<<<(E_TOT + 255) / 256, 256, 0, stream>>>(ei, rnk, rowptr,
                                                         a_src1, a_dst1, esw);
  agg1_kernel<<<N_NODES / 16, 256, 0, stream>>>(h1u, esw, rowptr, bias1, W2,
                                                att_src2, att_dst2, hs2);
  agg2_kernel<<<(N_NODES + 15) / 16, 256, 0, stream>>>(hs2, rowptr, esw, bias2, out);
}

// Round 5
// 306.416 us; speedup vs baseline: 1.0069x; 1.0069x over previous
//
#include <hip/hip_runtime.h>

#define N_NODES 50000
#define N_EDGES 800000
#define E_TOT   850000   /* N_EDGES + N_NODES self-loops */
#define C_IN    512
#define C_HID   128
#define NEG     0.2f

typedef _Float16 f16x8 __attribute__((ext_vector_type(8)));
typedef __attribute__((ext_vector_type(4))) float f32x4;

__device__ __forceinline__ float leaky(float x) { return x > 0.f ? x : NEG * x; }

union U32H2 { unsigned u; _Float16 h[2]; float f; };
union BFrag { uint4 u; f16x8 h; };

__device__ __forceinline__ unsigned short f2h(float f) {
  U32H2 c; c.h[0] = (_Float16)f; return (unsigned short)(c.u & 0xffff);
}

// pack two fp32 -> fp16x2 (RTZ hardware op) as raw u32
__device__ __forceinline__ unsigned pk2h(float a, float b) {
  union { __fp16 v __attribute__((ext_vector_type(2))); unsigned u; } c;
  c.v = __builtin_amdgcn_cvt_pkrtz(a, b);
  return c.u;
}

// Full 16-lane (DPP row) all-reduce add on the VALU pipe — zero DS ops.
// Stages: quad xor1, quad xor2, row_ror:4, row_ror:8.
__device__ __forceinline__ float row_reduce_add(float v) {
  union { float f; int i; } a, b;
  a.f = v;
  b.i = __builtin_amdgcn_update_dpp(0, a.i, 0xB1, 0xF, 0xF, true);  a.f += b.f;
  b.i = __builtin_amdgcn_update_dpp(0, a.i, 0x4E, 0xF, 0xF, true);  a.f += b.f;
  b.i = __builtin_amdgcn_update_dpp(0, a.i, 0x124, 0xF, 0xF, true); a.f += b.f;
  b.i = __builtin_amdgcn_update_dpp(0, a.i, 0x128, 0xF, 0xF, true); a.f += b.f;
  return a.f;
}

// ---------------------------------------------------------------------------
// setup: fuses prep_w (blocks 0..31), prep_v (32..159), deg+rank (160..3284).
// ---------------------------------------------------------------------------
__global__ __launch_bounds__(256) void setup_kernel(
    const float* __restrict__ W1, const float* __restrict__ as1,
    const float* __restrict__ ad1, const int* __restrict__ ei,
    unsigned short* __restrict__ Wswz, float* __restrict__ v1s, float* __restrict__ v1d,
    int* __restrict__ deg, int* __restrict__ rnk) {
  const int b = blockIdx.x;
  if (b < 32) {
    int t = b * 256 + threadIdx.x;                 // 8192 threads
    int c = t >> 6, kc = t & 63;
    if (c >= C_HID) return;
    int kblk = kc >> 2, q = kc & 3;
    int ct = c >> 4, l15 = c & 15;
    int lane = q * 16 + l15;
    unsigned short hb[8], lb[8];
#pragma unroll
    for (int i = 0; i < 8; i++) {
      float w = W1[(size_t)(kc * 8 + i) * C_HID + c];
      _Float16 hi = (_Float16)w;                   // RNE
      _Float16 lo = (_Float16)(w - (float)hi);
      U32H2 ch; ch.h[0] = hi;
      U32H2 cl; cl.h[0] = lo;
      hb[i] = (unsigned short)(ch.u & 0xffff);
      lb[i] = (unsigned short)(cl.u & 0xffff);
    }
    size_t chunk0 = ((size_t)(kblk * 8 + ct) * 2) * 512;
    *(uint4*)&Wswz[chunk0 + (size_t)lane * 8]       = *(uint4*)hb;
    *(uint4*)&Wswz[chunk0 + 512 + (size_t)lane * 8] = *(uint4*)lb;
  } else if (b < 160) {
    const int wv = threadIdx.x >> 6, lane = threadIdx.x & 63;
    const int k = (b - 32) * 4 + wv;
    if (k >= C_IN) return;
    float2 w = *(const float2*)(W1 + (size_t)k * C_HID + 2 * lane);
    float2 a = *(const float2*)(as1 + 2 * lane);
    float2 d = *(const float2*)(ad1 + 2 * lane);
    float s = w.x * a.x + w.y * a.y;
    float t = w.x * d.x + w.y * d.y;
#pragma unroll
    for (int m = 32; m >= 1; m >>= 1) {
      s += __shfl_xor(s, m, 64);
      t += __shfl_xor(t, m, 64);
    }
    if (lane == 0) { v1s[k] = s; v1d[k] = t; }
  } else {
    int e = (b - 160) * 256 + threadIdx.x;
    if (e < N_EDGES) rnk[e] = atomicAdd(&deg[ei[N_EDGES + e]], 1);
  }
}

// ---------------------------------------------------------------------------
// lin1: h1 = x @ W1 via fp16 MFMA (x_h*W_hi + x_h*W_lo), fused fp32 a_src/a_dst.
// Round-3 LDS-staged structure (measured best) re-tiled for TLP: block =
// 32 rows x 128 cols (was 64 rows) -> grid 1564 blocks = 6.1 blocks/CU (was
// 3.06): latency + barriers now hidden by co-resident blocks, and the 4-vs-3
// blocks/CU quantization tail shrinks from ~33% to ~16%. LDS 5 KB.
// Each thread stages 4 floats/kblk (uint2); wave computes 32 rows x 32 cols
// (2 row-frags x 2 col-tiles x hi/lo = 8 MFMAs/kblk, 4 B-loads from L2).
// Block 0 runs the rowptr scan (hidden under the GEMM blocks).
// ---------------------------------------------------------------------------
__global__ __launch_bounds__(256) void lin1_kernel(const float* __restrict__ x,
    const unsigned short* __restrict__ Wswz,
    const float* __restrict__ v1s, const float* __restrict__ v1d,
    unsigned short* __restrict__ h1u, float* __restrict__ a_src, float* __restrict__ a_dst,
    const int* __restrict__ deg, int* __restrict__ rowptr) {
  __shared__ __attribute__((aligned(16))) unsigned short As[2][32][40];  // 5 KB
  __shared__ int wsum[4];

  if (blockIdx.x == 0) {
    // ---- scan block: exclusive prefix of (deg+1) over 50000 nodes ----
    const int tid = threadIdx.x, lane = tid & 63, wv = tid >> 6;
    int carry = 0;
    for (int base = 0; base < N_NODES; base += 8192) {
      int i0 = base + tid * 32;
      int v[32];
      if (i0 + 32 <= N_NODES) {
#pragma unroll
        for (int k = 0; k < 8; k++) {
          int4 t4 = *(const int4*)(deg + i0 + 4 * k);
          v[4 * k]     = t4.x + 1; v[4 * k + 1] = t4.y + 1;
          v[4 * k + 2] = t4.z + 1; v[4 * k + 3] = t4.w + 1;
        }
      } else {
#pragma unroll
        for (int k = 0; k < 32; k++) v[k] = (i0 + k < N_NODES) ? deg[i0 + k] + 1 : 0;
      }
      int tsum = 0;
#pragma unroll
      for (int k = 0; k < 32; k++) tsum += v[k];
      int sc = tsum;                                   // inclusive scan of thread sums
#pragma unroll
      for (int off = 1; off < 64; off <<= 1) {
        int t = __shfl_up(sc, off, 64);
        if (lane >= off) sc += t;
      }
      if (lane == 63) wsum[wv] = sc;
      __syncthreads();
      if (tid < 4) {
        int s = wsum[tid];
#pragma unroll
        for (int off = 1; off < 4; off <<= 1) {
          int t = __shfl_up(s, off, 64);
          if (tid >= off) s += t;
        }
        wsum[tid] = s;
      }
      __syncthreads();
      int run = carry + (wv ? wsum[wv - 1] : 0) + sc - tsum;   // exclusive base
      if (i0 + 32 <= N_NODES) {
#pragma unroll
        for (int k = 0; k < 8; k++) {
          int4 w4;
          w4.x = run; run += v[4 * k];
          w4.y = run; run += v[4 * k + 1];
          w4.z = run; run += v[4 * k + 2];
          w4.w = run; run += v[4 * k + 3];
          *(int4*)(rowptr + i0 + 4 * k) = w4;
        }
      } else {
#pragma unroll
        for (int k = 0; k < 32; k++) {
          if (i0 + k < N_NODES) rowptr[i0 + k] = run;
          run += v[k];
        }
      }
      carry += wsum[3];
      __syncthreads();
    }
    if (tid == 0) rowptr[N_NODES] = carry;
    return;
  }

  const int tid  = threadIdx.x;
  const int lane = tid & 63, wv = tid >> 6;
  const int m0   = (blockIdx.x - 1) * 32;

  const int arow = tid >> 3, kseg = (tid & 7) * 4;   // 32 rows x 8 segs of 4 floats
  int grow = m0 + arow;
  if (grow >= N_NODES) grow = N_NODES - 1;          // clamp; stores guarded
  const float* xrow = x + (size_t)grow * C_IN + kseg;

  f32x4 acc[2][2];
#pragma unroll
  for (int rf = 0; rf < 2; rf++) { acc[rf][0] = (f32x4)0.f; acc[rf][1] = (f32x4)0.f; }
  float ps = 0.f, pd = 0.f;

  const int q = lane >> 4, l15 = lane & 15;

  float4 xa = *(const float4*)(xrow);

#pragma unroll
  for (int kblk = 0; kblk < 16; kblk++) {
    const int k0 = kblk * 32;
    const int buf = kblk & 1;
    float4 vsa = *(const float4*)(v1s + k0 + kseg);
    float4 vda = *(const float4*)(v1d + k0 + kseg);
    ps += xa.x * vsa.x + xa.y * vsa.y + xa.z * vsa.z + xa.w * vsa.w;
    pd += xa.x * vda.x + xa.y * vda.y + xa.z * vda.z + xa.w * vda.w;
    *(uint2*)&As[buf][arow][kseg] = make_uint2(pk2h(xa.x, xa.y), pk2h(xa.z, xa.w));
    __syncthreads();                                // As[buf] ready
    if (kblk < 15) {                                // prefetch next x chunk
      xa = *(const float4*)(xrow + k0 + 32);
    }

    // B fragments: wave's 2 col-tiles, hi+lo each (L2-resident Wswz)
    const unsigned short* bp = Wswz + ((size_t)(kblk * 8 + wv * 2) * 2) * 512 + (size_t)lane * 8;
    BFrag b00, b01, b10, b11;
    b00.u = *(const uint4*)(bp);
    b01.u = *(const uint4*)(bp + 512);
    b10.u = *(const uint4*)(bp + 1024);
    b11.u = *(const uint4*)(bp + 1536);

#pragma unroll
    for (int rf = 0; rf < 2; rf++) {
      f16x8 af = *(const f16x8*)&As[buf][rf * 16 + l15][q * 8];
      acc[rf][0] = __builtin_amdgcn_mfma_f32_16x16x32_f16(af, b00.h, acc[rf][0], 0, 0, 0);
      acc[rf][0] = __builtin_amdgcn_mfma_f32_16x16x32_f16(af, b01.h, acc[rf][0], 0, 0, 0);
      acc[rf][1] = __builtin_amdgcn_mfma_f32_16x16x32_f16(af, b10.h, acc[rf][1], 0, 0, 0);
      acc[rf][1] = __builtin_amdgcn_mfma_f32_16x16x32_f16(af, b11.h, acc[rf][1], 0, 0, 0);
    }
  }

  // attention dots: reduce over the 8 staging threads sharing a row
  ps += __shfl_xor(ps, 1, 64); ps += __shfl_xor(ps, 2, 64); ps += __shfl_xor(ps, 4, 64);
  pd += __shfl_xor(pd, 1, 64); pd += __shfl_xor(pd, 2, 64); pd += __shfl_xor(pd, 4, 64);
  if ((tid & 7) == 0) {
    int row = m0 + arow;
    if (row < N_NODES) { a_src[row] = ps; a_dst[row] = pd; }
  }

  // C store (fp16): C/D layout col=lane&15, row=(lane>>4)*4+reg
#pragma unroll
  for (int rf = 0; rf < 2; rf++) {
    int rbase = m0 + rf * 16 + q * 4;
#pragma unroll
    for (int ct = 0; ct < 2; ct++) {
      int col = wv * 32 + ct * 16 + l15;
#pragma unroll
      for (int ri = 0; ri < 4; ri++) {
        int row = rbase + ri;
        if (row < N_NODES)
          h1u[(size_t)row * C_HID + col] = f2h(acc[rf][ct][ri]);
      }
    }
  }
}

// ---------------------------------------------------------------------------
// bucket: no atomics. Edge e -> slot rowptr[dst]+rank[e]; self-loop n -> slot
// rowptr[n+1]-1. Weight w = exp(leaky(a_src+a_dst)) fused in.
// ---------------------------------------------------------------------------
__global__ void bucket_kernel(const int* __restrict__ ei, const int* __restrict__ rnk,
                              const int* __restrict__ rowptr,
                              const float* __restrict__ a_src, const float* __restrict__ a_dst,
                              int2* __restrict__ esw) {
  int e = blockIdx.x * blockDim.x + threadIdx.x;
  if (e >= E_TOT) return;
  int src, slot;
  if (e < N_EDGES) {
    src = ei[e];
    int dst = ei[N_EDGES + e];
    slot = rowptr[dst] + rnk[e];
    U32H2 c; c.f = __expf(leaky(a_src[src] + a_dst[dst]));
    esw[slot] = make_int2(src, (int)c.u);
  } else {
    int n = e - N_EDGES;
    slot = rowptr[n + 1] - 1;
    U32H2 c; c.f = __expf(leaky(a_src[n] + a_dst[n]));
    esw[slot] = make_int2(n, (int)c.u);
  }
}

// ---------------------------------------------------------------------------
// agg1: 16 lanes per node (4 nodes/wave), lane r owns channels r*8..r*8+7.
// ZERO DS ops: edge records read via same-address broadcast loads (L1-hot
// bucket lines) so every lane sees every (s,w) -> no s/w shuffles, no acc
// fold, and wsum needs no reduction. Per 8-edge round: 8 record loads + 8
// independent 16-B gathers in flight per lane. Padded slots clamp to the
// bucket's first record (one hot line) with w=0. Epilogue p-fold uses DPP
// row reduction (VALU pipe). hs2[n] = {p0..p5, as0..as2, ad0..ad2}.
// ---------------------------------------------------------------------------
__global__ __launch_bounds__(256) void agg1_kernel(const unsigned short* __restrict__ h1u,
    const int2* __restrict__ esw, const int* __restrict__ rowptr,
    const float* __restrict__ bias1, const float* __restrict__ W2,
    const float* __restrict__ as2w, const float* __restrict__ ad2w,
    float* __restrict__ hs2) {
  const int wv = threadIdx.x >> 6, lane = threadIdx.x & 63;
  const int r = lane & 15;
  const int n = blockIdx.x * 16 + wv * 4 + (lane >> 4);   // grid covers N exactly
  const int start = rowptr[n], end = rowptr[n + 1];

  const unsigned short* hbase = h1u + r * 8;

  float acc[8] = {0, 0, 0, 0, 0, 0, 0, 0};
  float wsum = 0.f;
  for (int base = start; base < end; base += 8) {
    const int cnt = end - base;                    // group-uniform
    int2 rec[8];
#pragma unroll
    for (int j = 0; j < 8; j++)
      rec[j] = esw[j < cnt ? base + j : base];     // clamp: bucket's first record
    uint4 g[8];
#pragma unroll
    for (int j = 0; j < 8; j++)
      g[j] = *(const uint4*)(hbase + (size_t)rec[j].x * C_HID);
#pragma unroll
    for (int j = 0; j < 8; j++) {
      U32H2 cw; cw.u = (unsigned)rec[j].y;
      const float W = (j < cnt) ? cw.f : 0.f;
      wsum += W;
      U32H2 c0, c1, c2, c3;
      c0.u = g[j].x; c1.u = g[j].y; c2.u = g[j].z; c3.u = g[j].w;
      acc[0] = fmaf(W, (float)c0.h[0], acc[0]); acc[1] = fmaf(W, (float)c0.h[1], acc[1]);
      acc[2] = fmaf(W, (float)c1.h[0], acc[2]); acc[3] = fmaf(W, (float)c1.h[1], acc[3]);
      acc[4] = fmaf(W, (float)c2.h[0], acc[4]); acc[5] = fmaf(W, (float)c2.h[1], acc[5]);
      acc[6] = fmaf(W, (float)c3.h[0], acc[6]); acc[7] = fmaf(W, (float)c3.h[1], acc[7]);
    }
  }

  const float inv = 1.f / wsum;                    // > 0 via self-loop; uniform in group

  float4 ba = *(const float4*)(bias1 + r * 8);
  float4 bb = *(const float4*)(bias1 + r * 8 + 4);
  float u[8] = {fmaxf(acc[0] * inv + ba.x, 0.f), fmaxf(acc[1] * inv + ba.y, 0.f),
                fmaxf(acc[2] * inv + ba.z, 0.f), fmaxf(acc[3] * inv + ba.w, 0.f),
                fmaxf(acc[4] * inv + bb.x, 0.f), fmaxf(acc[5] * inv + bb.y, 0.f),
                fmaxf(acc[6] * inv + bb.z, 0.f), fmaxf(acc[7] * inv + bb.w, 0.f)};
  float p[6] = {0, 0, 0, 0, 0, 0};
#pragma unroll
  for (int j = 0; j < 8; j++) {
    const float* w2r = W2 + (size_t)(r * 8 + j) * 6;   // L1-hot (3 KB total)
#pragma unroll
    for (int o = 0; o < 6; o++) p[o] = fmaf(u[j], w2r[o], p[o]);
  }
  // fold over the 16 lanes of the group — DPP, zero DS ops
#pragma unroll
  for (int o = 0; o < 6; o++) p[o] = row_reduce_add(p[o]);

  if (r == 0) {
    float as0 = p[0] * as2w[0] + p[1] * as2w[1];
    float as1 = p[2] * as2w[2] + p[3] * as2w[3];
    float as2_ = p[4] * as2w[4] + p[5] * as2w[5];
    float ad0 = p[0] * ad2w[0] + p[1] * ad2w[1];
    float ad1 = p[2] * ad2w[2] + p[3] * ad2w[3];
    float ad2_ = p[4] * ad2w[4] + p[5] * ad2w[5];
    float* dst = hs2 + (size_t)n * 12;
    *(float4*)(dst)     = make_float4(p[0], p[1], p[2], p[3]);
    *(float4*)(dst + 4) = make_float4(p[4], p[5], as0, as1);
    *(float4*)(dst + 8) = make_float4(as2_, ad0, ad1, ad2_);
  }
}

// ---------------------------------------------------------------------------
// agg2: 16 lanes per node (4 nodes/wave); per edge ONE 48-B packed record
// {p0..p5, as0..as2} (3 loads, 1-2 lines). Folds via DPP row reduction.
// out = mean over heads + bias2.
// ---------------------------------------------------------------------------
__global__ __launch_bounds__(256) void agg2_kernel(const float* __restrict__ hs2,
    const int* __restrict__ rowptr, const int2* __restrict__ esw,
    const float* __restrict__ bias2, float* __restrict__ out) {
  const int wv = threadIdx.x >> 6, lane = threadIdx.x & 63;
  const int q = lane >> 4, r = lane & 15;
  const int n = blockIdx.x * 16 + wv * 4 + q;
  if (n >= N_NODES) return;
  const int start = rowptr[n], end = rowptr[n + 1];
  float4 own = *(const float4*)(hs2 + (size_t)n * 12 + 8);   // {as2, ad0, ad1, ad2}
  const float ad0 = own.y, ad1 = own.z, ad2 = own.w;

  float d0 = 0.f, d1 = 0.f, d2 = 0.f;
  float a0 = 0.f, a1 = 0.f, a2 = 0.f, a3 = 0.f, a4 = 0.f, a5 = 0.f;
  for (int j = start + r; j < end; j += 16) {
    int s = esw[j].x;
    const float* rec = hs2 + (size_t)s * 12;
    float4 A = *(const float4*)(rec);          // p0..p3
    float4 B = *(const float4*)(rec + 4);      // p4, p5, as0, as1
    float  C = rec[8];                         // as2
    float e0 = __expf(leaky(B.z + ad0));
    float e1 = __expf(leaky(B.w + ad1));
    float e2 = __expf(leaky(C + ad2));
    d0 += e0; d1 += e1; d2 += e2;
    a0 += e0 * A.x; a1 += e0 * A.y;
    a2 += e1 * A.z; a3 += e1 * A.w;
    a4 += e2 * B.x; a5 += e2 * B.y;
  }
  d0 = row_reduce_add(d0); d1 = row_reduce_add(d1); d2 = row_reduce_add(d2);
  a0 = row_reduce_add(a0); a1 = row_reduce_add(a1); a2 = row_reduce_add(a2);
  a3 = row_reduce_add(a3); a4 = row_reduce_add(a4); a5 = row_reduce_add(a5);
  if (r == 0) {
    float o0 = (a0 / d0 + a2 / d1 + a4 / d2) * (1.f / 3.f) + bias2[0];
    float o1 = (a1 / d0 + a3 / d1 + a5 / d2) * (1.f / 3.f) + bias2[1];
    *(float2*)(out + (size_t)n * 2) = make_float2(o0, o1);
  }
}

// ---------------------------------------------------------------------------
extern "C" void kernel_launch(void* const* d_in, const int* in_sizes, int n_in,
                              void* d_out, int out_size, void* d_ws, size_t ws_size,
                              hipStream_t stream) {
  const float* x        = (const float*)d_in[0];
  const int*   ei       = (const int*)d_in[1];
  const float* W1       = (const float*)d_in[2];
  const float* att_src1 = (const float*)d_in[3];
  const float* att_dst1 = (const float*)d_in[4];
  const float* bias1    = (const float*)d_in[5];
  const float* W2       = (const float*)d_in[6];
  const float* att_src2 = (const float*)d_in[7];
  const float* att_dst2 = (const float*)d_in[8];
  const float* bias2    = (const float*)d_in[9];
  float* out = (float*)d_out;

  char* w = (char*)d_ws;
  auto alloc = [&](size_t bytes) {
    char* p = w;
    w += (bytes + 255) & ~(size_t)255;
    return p;
  };
  unsigned short* h1u    = (unsigned short*)alloc((size_t)N_NODES * C_HID * 2);  // 12.8 MB
  unsigned short* Wswz   = (unsigned short*)alloc((size_t)C_IN * C_HID * 2 * 2); // 256 KB
  float*          v1s    = (float*)alloc((size_t)C_IN * 4);
  float*          v1d    = (float*)alloc((size_t)C_IN * 4);
  float*          a_src1 = (float*)alloc((size_t)N_NODES * 4);
  float*          a_dst1 = (float*)alloc((size_t)N_NODES * 4);
  int*            deg    = (int*)alloc((size_t)N_NODES * 4);
  int*            rowptr = (int*)alloc((size_t)(N_NODES + 4) * 4);
  int*            rnk    = (int*)alloc((size_t)N_EDGES * 4);                     // 3.2 MB
  int2*           esw    = (int2*)alloc((size_t)E_TOT * 8);                      // 6.8 MB
  float*          hs2    = (float*)alloc((size_t)N_NODES * 12 * 4);              // 2.4 MB

  (void)hipMemsetAsync(deg, 0, (size_t)N_NODES * 4, stream);

  setup_kernel<<<160 + (N_EDGES + 255) / 256, 256, 0, stream>>>(
      W1, att_src1, att_dst1, ei, Wswz, v1s, v1d, deg, rnk);
  // scan folded into lin1's block 0 (runs concurrent with the GEMM blocks)
  lin1_kernel<<<(N_NODES + 31) / 32 + 1, 256, 0, stream>>>(x, Wswz, v1s, v1d,
                                                           h1u, a_src1, a_dst1,
                                                           deg, rowptr);
  bucket_kernel<<<(E_TOT + 255) / 256, 256, 0, stream>>>(ei, rnk, rowptr,
                                                         a_src1, a_dst1, esw);
  agg1_kernel<<<N_NODES / 16, 256, 0, stream>>>(h1u, esw, rowptr, bias1, W2,
                                                att_src2, att_dst2, hs2);
  agg2_kernel<<<(N_NODES + 15) / 16, 256, 0, stream>>>(hs2, rowptr, esw, bias2, out);
}

// Round 6
// 301.559 us; speedup vs baseline: 1.0231x; 1.0161x over previous
//
#include <hip/hip_runtime.h>

#define N_NODES 50000
#define N_EDGES 800000
#define E_TOT   850000   /* N_EDGES + N_NODES self-loops */
#define C_IN    512
#define C_HID   128
#define NEG     0.2f

typedef _Float16 f16x8 __attribute__((ext_vector_type(8)));
typedef __attribute__((ext_vector_type(4))) float f32x4;

__device__ __forceinline__ float leaky(float x) { return x > 0.f ? x : NEG * x; }

union U32H2 { unsigned u; _Float16 h[2]; float f; };
union BFrag { uint4 u; f16x8 h; };

__device__ __forceinline__ unsigned short f2h(float f) {
  U32H2 c; c.h[0] = (_Float16)f; return (unsigned short)(c.u & 0xffff);
}

// pack two fp32 -> fp16x2 (RTZ hardware op) as raw u32
__device__ __forceinline__ unsigned pk2h(float a, float b) {
  union { __fp16 v __attribute__((ext_vector_type(2))); unsigned u; } c;
  c.v = __builtin_amdgcn_cvt_pkrtz(a, b);
  return c.u;
}

// Full 16-lane (DPP row) all-reduce add on the VALU pipe — zero DS ops.
// Stages: quad xor1, quad xor2, row_ror:4, row_ror:8.
__device__ __forceinline__ float row_reduce_add(float v) {
  union { float f; int i; } a, b;
  a.f = v;
  b.i = __builtin_amdgcn_update_dpp(0, a.i, 0xB1, 0xF, 0xF, true);  a.f += b.f;
  b.i = __builtin_amdgcn_update_dpp(0, a.i, 0x4E, 0xF, 0xF, true);  a.f += b.f;
  b.i = __builtin_amdgcn_update_dpp(0, a.i, 0x124, 0xF, 0xF, true); a.f += b.f;
  b.i = __builtin_amdgcn_update_dpp(0, a.i, 0x128, 0xF, 0xF, true); a.f += b.f;
  return a.f;
}

// ---------------------------------------------------------------------------
// setup: fuses prep_w (blocks 0..31), prep_v (32..159), deg+rank (160..3284).
// ---------------------------------------------------------------------------
__global__ __launch_bounds__(256) void setup_kernel(
    const float* __restrict__ W1, const float* __restrict__ as1,
    const float* __restrict__ ad1, const int* __restrict__ ei,
    unsigned short* __restrict__ Wswz, float* __restrict__ v1s, float* __restrict__ v1d,
    int* __restrict__ deg, int* __restrict__ rnk) {
  const int b = blockIdx.x;
  if (b < 32) {
    int t = b * 256 + threadIdx.x;                 // 8192 threads
    int c = t >> 6, kc = t & 63;
    if (c >= C_HID) return;
    int kblk = kc >> 2, q = kc & 3;
    int ct = c >> 4, l15 = c & 15;
    int lane = q * 16 + l15;
    unsigned short hb[8], lb[8];
#pragma unroll
    for (int i = 0; i < 8; i++) {
      float w = W1[(size_t)(kc * 8 + i) * C_HID + c];
      _Float16 hi = (_Float16)w;                   // RNE
      _Float16 lo = (_Float16)(w - (float)hi);
      U32H2 ch; ch.h[0] = hi;
      U32H2 cl; cl.h[0] = lo;
      hb[i] = (unsigned short)(ch.u & 0xffff);
      lb[i] = (unsigned short)(cl.u & 0xffff);
    }
    size_t chunk0 = ((size_t)(kblk * 8 + ct) * 2) * 512;
    *(uint4*)&Wswz[chunk0 + (size_t)lane * 8]       = *(uint4*)hb;
    *(uint4*)&Wswz[chunk0 + 512 + (size_t)lane * 8] = *(uint4*)lb;
  } else if (b < 160) {
    const int wv = threadIdx.x >> 6, lane = threadIdx.x & 63;
    const int k = (b - 32) * 4 + wv;
    if (k >= C_IN) return;
    float2 w = *(const float2*)(W1 + (size_t)k * C_HID + 2 * lane);
    float2 a = *(const float2*)(as1 + 2 * lane);
    float2 d = *(const float2*)(ad1 + 2 * lane);
    float s = w.x * a.x + w.y * a.y;
    float t = w.x * d.x + w.y * d.y;
#pragma unroll
    for (int m = 32; m >= 1; m >>= 1) {
      s += __shfl_xor(s, m, 64);
      t += __shfl_xor(t, m, 64);
    }
    if (lane == 0) { v1s[k] = s; v1d[k] = t; }
  } else {
    int e = (b - 160) * 256 + threadIdx.x;
    if (e < N_EDGES) rnk[e] = atomicAdd(&deg[ei[N_EDGES + e]], 1);
  }
}

// ---------------------------------------------------------------------------
// lin1: h1 = x @ W1 via fp16 MFMA (x_h*W_hi + x_h*W_lo), fused fp32 a_src/a_dst.
// ROUND-3 structure (measured best: 61 us): block 64x128, 4 waves; wave owns
// 64 rows x 32 cols; B direct global->reg (Wswz, L2-resident); double-buffered
// As -> ONE barrier per kblk; x prefetch after the barrier. Block 0 runs the
// rowptr scan (32 elems/thread -> 7 serial chunks), hidden under the GEMM.
// ---------------------------------------------------------------------------
__global__ __launch_bounds__(256) void lin1_kernel(const float* __restrict__ x,
    const unsigned short* __restrict__ Wswz,
    const float* __restrict__ v1s, const float* __restrict__ v1d,
    unsigned short* __restrict__ h1u, float* __restrict__ a_src, float* __restrict__ a_dst,
    const int* __restrict__ deg, int* __restrict__ rowptr) {
  __shared__ __attribute__((aligned(16))) unsigned short As[2][64][40];  // 10 KB
  __shared__ int wsum[4];

  if (blockIdx.x == 0) {
    // ---- scan block: exclusive prefix of (deg+1) over 50000 nodes ----
    const int tid = threadIdx.x, lane = tid & 63, wv = tid >> 6;
    int carry = 0;
    for (int base = 0; base < N_NODES; base += 8192) {
      int i0 = base + tid * 32;
      int v[32];
      if (i0 + 32 <= N_NODES) {
#pragma unroll
        for (int k = 0; k < 8; k++) {
          int4 t4 = *(const int4*)(deg + i0 + 4 * k);
          v[4 * k]     = t4.x + 1; v[4 * k + 1] = t4.y + 1;
          v[4 * k + 2] = t4.z + 1; v[4 * k + 3] = t4.w + 1;
        }
      } else {
#pragma unroll
        for (int k = 0; k < 32; k++) v[k] = (i0 + k < N_NODES) ? deg[i0 + k] + 1 : 0;
      }
      int tsum = 0;
#pragma unroll
      for (int k = 0; k < 32; k++) tsum += v[k];
      int sc = tsum;                                   // inclusive scan of thread sums
#pragma unroll
      for (int off = 1; off < 64; off <<= 1) {
        int t = __shfl_up(sc, off, 64);
        if (lane >= off) sc += t;
      }
      if (lane == 63) wsum[wv] = sc;
      __syncthreads();
      if (tid < 4) {
        int s = wsum[tid];
#pragma unroll
        for (int off = 1; off < 4; off <<= 1) {
          int t = __shfl_up(s, off, 64);
          if (tid >= off) s += t;
        }
        wsum[tid] = s;
      }
      __syncthreads();
      int run = carry + (wv ? wsum[wv - 1] : 0) + sc - tsum;   // exclusive base
      if (i0 + 32 <= N_NODES) {
#pragma unroll
        for (int k = 0; k < 8; k++) {
          int4 w4;
          w4.x = run; run += v[4 * k];
          w4.y = run; run += v[4 * k + 1];
          w4.z = run; run += v[4 * k + 2];
          w4.w = run; run += v[4 * k + 3];
          *(int4*)(rowptr + i0 + 4 * k) = w4;
        }
      } else {
#pragma unroll
        for (int k = 0; k < 32; k++) {
          if (i0 + k < N_NODES) rowptr[i0 + k] = run;
          run += v[k];
        }
      }
      carry += wsum[3];
      __syncthreads();
    }
    if (tid == 0) rowptr[N_NODES] = carry;
    return;
  }

  const int tid  = threadIdx.x;
  const int lane = tid & 63, wv = tid >> 6;
  const int m0   = (blockIdx.x - 1) * 64;

  const int arow = tid >> 2, kseg = (tid & 3) * 8;
  int grow = m0 + arow;
  if (grow >= N_NODES) grow = N_NODES - 1;          // clamp; stores guarded
  const float* xrow = x + (size_t)grow * C_IN + kseg;

  f32x4 acc[4][2];
#pragma unroll
  for (int rt = 0; rt < 4; rt++) { acc[rt][0] = (f32x4)0.f; acc[rt][1] = (f32x4)0.f; }
  float ps = 0.f, pd = 0.f;

  const int q = lane >> 4, l15 = lane & 15;

  float4 xa = *(const float4*)(xrow);
  float4 xb = *(const float4*)(xrow + 4);

#pragma unroll
  for (int kblk = 0; kblk < 16; kblk++) {
    const int k0 = kblk * 32;
    const int buf = kblk & 1;
    float4 vsa = *(const float4*)(v1s + k0 + kseg);
    float4 vsb = *(const float4*)(v1s + k0 + kseg + 4);
    float4 vda = *(const float4*)(v1d + k0 + kseg);
    float4 vdb = *(const float4*)(v1d + k0 + kseg + 4);
    ps += xa.x * vsa.x + xa.y * vsa.y + xa.z * vsa.z + xa.w * vsa.w
        + xb.x * vsb.x + xb.y * vsb.y + xb.z * vsb.z + xb.w * vsb.w;
    pd += xa.x * vda.x + xa.y * vda.y + xa.z * vda.z + xa.w * vda.w
        + xb.x * vdb.x + xb.y * vdb.y + xb.z * vdb.z + xb.w * vdb.w;
    *(uint4*)&As[buf][arow][kseg] = make_uint4(pk2h(xa.x, xa.y), pk2h(xa.z, xa.w),
                                               pk2h(xb.x, xb.y), pk2h(xb.z, xb.w));
    __syncthreads();                                // As[buf] ready
    if (kblk < 15) {                                // prefetch next x chunk
      xa = *(const float4*)(xrow + k0 + 32);
      xb = *(const float4*)(xrow + k0 + 36);
    }

    const unsigned short* bp = Wswz + ((size_t)(kblk * 8 + wv * 2) * 2) * 512 + (size_t)lane * 8;
    BFrag b00, b01, b10, b11;
    b00.u = *(const uint4*)(bp);
    b01.u = *(const uint4*)(bp + 512);
    b10.u = *(const uint4*)(bp + 1024);
    b11.u = *(const uint4*)(bp + 1536);

#pragma unroll
    for (int rt = 0; rt < 4; rt++) {
      f16x8 af = *(const f16x8*)&As[buf][rt * 16 + l15][q * 8];
      acc[rt][0] = __builtin_amdgcn_mfma_f32_16x16x32_f16(af, b00.h, acc[rt][0], 0, 0, 0);
      acc[rt][0] = __builtin_amdgcn_mfma_f32_16x16x32_f16(af, b01.h, acc[rt][0], 0, 0, 0);
      acc[rt][1] = __builtin_amdgcn_mfma_f32_16x16x32_f16(af, b10.h, acc[rt][1], 0, 0, 0);
      acc[rt][1] = __builtin_amdgcn_mfma_f32_16x16x32_f16(af, b11.h, acc[rt][1], 0, 0, 0);
    }
  }

  // attention dots: reduce over the 4 staging threads sharing a row
  ps += __shfl_xor(ps, 1, 64); ps += __shfl_xor(ps, 2, 64);
  pd += __shfl_xor(pd, 1, 64); pd += __shfl_xor(pd, 2, 64);
  if ((tid & 3) == 0) {
    int row = m0 + arow;
    if (row < N_NODES) { a_src[row] = ps; a_dst[row] = pd; }
  }

  // C store (fp16): C/D layout col=lane&15, row=(lane>>4)*4+reg
#pragma unroll
  for (int rt = 0; rt < 4; rt++) {
    int rbase = m0 + rt * 16 + q * 4;
#pragma unroll
    for (int ct = 0; ct < 2; ct++) {
      int col = wv * 32 + ct * 16 + l15;
#pragma unroll
      for (int ri = 0; ri < 4; ri++) {
        int row = rbase + ri;
        if (row < N_NODES)
          h1u[(size_t)row * C_HID + col] = f2h(acc[rt][ct][ri]);
      }
    }
  }
}

// ---------------------------------------------------------------------------
// bucket: no atomics. Edge e -> slot rowptr[dst]+rank[e]; self-loop n -> slot
// rowptr[n+1]-1. Weight w = exp(leaky(a_src+a_dst)) fused in.
// ---------------------------------------------------------------------------
__global__ void bucket_kernel(const int* __restrict__ ei, const int* __restrict__ rnk,
                              const int* __restrict__ rowptr,
                              const float* __restrict__ a_src, const float* __restrict__ a_dst,
                              int2* __restrict__ esw) {
  int e = blockIdx.x * blockDim.x + threadIdx.x;
  if (e >= E_TOT) return;
  int src, slot;
  if (e < N_EDGES) {
    src = ei[e];
    int dst = ei[N_EDGES + e];
    slot = rowptr[dst] + rnk[e];
    U32H2 c; c.f = __expf(leaky(a_src[src] + a_dst[dst]));
    esw[slot] = make_int2(src, (int)c.u);
  } else {
    int n = e - N_EDGES;
    slot = rowptr[n + 1] - 1;
    U32H2 c; c.f = __expf(leaky(a_src[n] + a_dst[n]));
    esw[slot] = make_int2(n, (int)c.u);
  }
}

// ---------------------------------------------------------------------------
// agg1: 16 lanes per node-PAIR group (lane r owns channels r*8..r*8+7); each
// group processes TWO adjacent nodes (contiguous esw ranges) with their
// memory chains interleaved: per round, rec loads for both nodes, then
// gathers for both, then both FMA blocks -> 2 independent latency chains in
// flight per group (the per-round chain rec->gather->FMA was the exposed
// cost). ZERO DS ops (broadcast rec loads; DPP epilogue reduction).
// hs2[n] = {p0..p5, as0..as2, ad0..ad2}.
// ---------------------------------------------------------------------------
__global__ __launch_bounds__(256) void agg1_kernel(const unsigned short* __restrict__ h1u,
    const int2* __restrict__ esw, const int* __restrict__ rowptr,
    const float* __restrict__ bias1, const float* __restrict__ W2,
    const float* __restrict__ as2w, const float* __restrict__ ad2w,
    float* __restrict__ hs2) {
  const int wv = threadIdx.x >> 6, lane = threadIdx.x & 63;
  const int r = lane & 15;
  const int gid = blockIdx.x * 16 + wv * 4 + (lane >> 4);
  if (gid >= N_NODES / 2) return;
  const int n0 = gid * 2;
  const int s0 = rowptr[n0], e0 = rowptr[n0 + 1], e1 = rowptr[n0 + 2];

  const unsigned short* hbase = h1u + r * 8;

  float acc0[8] = {0, 0, 0, 0, 0, 0, 0, 0};
  float acc1[8] = {0, 0, 0, 0, 0, 0, 0, 0};
  float ws0 = 0.f, ws1 = 0.f;
  int b0 = s0, b1 = e0;

  while (b0 < e0 || b1 < e1) {
    const bool h0 = b0 < e0, h1 = b1 < e1;   // group-uniform
    int2 r0[8], r1[8];
    uint4 g0[8], g1[8];
    int c0 = 0, c1 = 0;
    if (h0) {
      c0 = min(e0 - b0, 8);
#pragma unroll
      for (int j = 0; j < 8; j++) r0[j] = esw[j < c0 ? b0 + j : b0];
    }
    if (h1) {
      c1 = min(e1 - b1, 8);
#pragma unroll
      for (int j = 0; j < 8; j++) r1[j] = esw[j < c1 ? b1 + j : b1];
    }
    if (h0) {
#pragma unroll
      for (int j = 0; j < 8; j++)
        g0[j] = *(const uint4*)(hbase + (size_t)r0[j].x * C_HID);
    }
    if (h1) {
#pragma unroll
      for (int j = 0; j < 8; j++)
        g1[j] = *(const uint4*)(hbase + (size_t)r1[j].x * C_HID);
    }
    if (h0) {
#pragma unroll
      for (int j = 0; j < 8; j++) {
        U32H2 cw; cw.u = (unsigned)r0[j].y;
        const float W = (j < c0) ? cw.f : 0.f;
        ws0 += W;
        U32H2 u0, u1, u2, u3;
        u0.u = g0[j].x; u1.u = g0[j].y; u2.u = g0[j].z; u3.u = g0[j].w;
        acc0[0] = fmaf(W, (float)u0.h[0], acc0[0]); acc0[1] = fmaf(W, (float)u0.h[1], acc0[1]);
        acc0[2] = fmaf(W, (float)u1.h[0], acc0[2]); acc0[3] = fmaf(W, (float)u1.h[1], acc0[3]);
        acc0[4] = fmaf(W, (float)u2.h[0], acc0[4]); acc0[5] = fmaf(W, (float)u2.h[1], acc0[5]);
        acc0[6] = fmaf(W, (float)u3.h[0], acc0[6]); acc0[7] = fmaf(W, (float)u3.h[1], acc0[7]);
      }
      b0 += 8;
    }
    if (h1) {
#pragma unroll
      for (int j = 0; j < 8; j++) {
        U32H2 cw; cw.u = (unsigned)r1[j].y;
        const float W = (j < c1) ? cw.f : 0.f;
        ws1 += W;
        U32H2 u0, u1, u2, u3;
        u0.u = g1[j].x; u1.u = g1[j].y; u2.u = g1[j].z; u3.u = g1[j].w;
        acc1[0] = fmaf(W, (float)u0.h[0], acc1[0]); acc1[1] = fmaf(W, (float)u0.h[1], acc1[1]);
        acc1[2] = fmaf(W, (float)u1.h[0], acc1[2]); acc1[3] = fmaf(W, (float)u1.h[1], acc1[3]);
        acc1[4] = fmaf(W, (float)u2.h[0], acc1[4]); acc1[5] = fmaf(W, (float)u2.h[1], acc1[5]);
        acc1[6] = fmaf(W, (float)u3.h[0], acc1[6]); acc1[7] = fmaf(W, (float)u3.h[1], acc1[7]);
      }
      b1 += 8;
    }
  }

  float4 ba = *(const float4*)(bias1 + r * 8);
  float4 bb = *(const float4*)(bias1 + r * 8 + 4);

  auto epilogue = [&](const float* acc, float wsum, int n) {
    const float inv = 1.f / wsum;                  // > 0 via self-loop
    float u[8] = {fmaxf(acc[0] * inv + ba.x, 0.f), fmaxf(acc[1] * inv + ba.y, 0.f),
                  fmaxf(acc[2] * inv + ba.z, 0.f), fmaxf(acc[3] * inv + ba.w, 0.f),
                  fmaxf(acc[4] * inv + bb.x, 0.f), fmaxf(acc[5] * inv + bb.y, 0.f),
                  fmaxf(acc[6] * inv + bb.z, 0.f), fmaxf(acc[7] * inv + bb.w, 0.f)};
    float p[6] = {0, 0, 0, 0, 0, 0};
#pragma unroll
    for (int j = 0; j < 8; j++) {
      const float* w2r = W2 + (size_t)(r * 8 + j) * 6;   // L1-hot (3 KB total)
#pragma unroll
      for (int o = 0; o < 6; o++) p[o] = fmaf(u[j], w2r[o], p[o]);
    }
#pragma unroll
    for (int o = 0; o < 6; o++) p[o] = row_reduce_add(p[o]);
    if (r == 0) {
      float as0 = p[0] * as2w[0] + p[1] * as2w[1];
      float as1 = p[2] * as2w[2] + p[3] * as2w[3];
      float as2_ = p[4] * as2w[4] + p[5] * as2w[5];
      float ad0 = p[0] * ad2w[0] + p[1] * ad2w[1];
      float ad1 = p[2] * ad2w[2] + p[3] * ad2w[3];
      float ad2_ = p[4] * ad2w[4] + p[5] * ad2w[5];
      float* dst = hs2 + (size_t)n * 12;
      *(float4*)(dst)     = make_float4(p[0], p[1], p[2], p[3]);
      *(float4*)(dst + 4) = make_float4(p[4], p[5], as0, as1);
      *(float4*)(dst + 8) = make_float4(as2_, ad0, ad1, ad2_);
    }
  };
  epilogue(acc0, ws0, n0);
  epilogue(acc1, ws1, n0 + 1);
}

// ---------------------------------------------------------------------------
// agg2: 16 lanes per node (4 nodes/wave); per edge ONE 48-B packed record
// {p0..p5, as0..as2} (3 loads, 1-2 lines). Folds via DPP row reduction.
// out = mean over heads + bias2.
// ---------------------------------------------------------------------------
__global__ __launch_bounds__(256) void agg2_kernel(const float* __restrict__ hs2,
    const int* __restrict__ rowptr, const int2* __restrict__ esw,
    const float* __restrict__ bias2, float* __restrict__ out) {
  const int wv = threadIdx.x >> 6, lane = threadIdx.x & 63;
  const int q = lane >> 4, r = lane & 15;
  const int n = blockIdx.x * 16 + wv * 4 + q;
  if (n >= N_NODES) return;
  const int start = rowptr[n], end = rowptr[n + 1];
  float4 own = *(const float4*)(hs2 + (size_t)n * 12 + 8);   // {as2, ad0, ad1, ad2}
  const float ad0 = own.y, ad1 = own.z, ad2 = own.w;

  float d0 = 0.f, d1 = 0.f, d2 = 0.f;
  float a0 = 0.f, a1 = 0.f, a2 = 0.f, a3 = 0.f, a4 = 0.f, a5 = 0.f;
  for (int j = start + r; j < end; j += 16) {
    int s = esw[j].x;
    const float* rec = hs2 + (size_t)s * 12;
    float4 A = *(const float4*)(rec);          // p0..p3
    float4 B = *(const float4*)(rec + 4);      // p4, p5, as0, as1
    float  C = rec[8];                         // as2
    float e0 = __expf(leaky(B.z + ad0));
    float e1 = __expf(leaky(B.w + ad1));
    float e2 = __expf(leaky(C + ad2));
    d0 += e0; d1 += e1; d2 += e2;
    a0 += e0 * A.x; a1 += e0 * A.y;
    a2 += e1 * A.z; a3 += e1 * A.w;
    a4 += e2 * B.x; a5 += e2 * B.y;
  }
  d0 = row_reduce_add(d0); d1 = row_reduce_add(d1); d2 = row_reduce_add(d2);
  a0 = row_reduce_add(a0); a1 = row_reduce_add(a1); a2 = row_reduce_add(a2);
  a3 = row_reduce_add(a3); a4 = row_reduce_add(a4); a5 = row_reduce_add(a5);
  if (r == 0) {
    float o0 = (a0 / d0 + a2 / d1 + a4 / d2) * (1.f / 3.f) + bias2[0];
    float o1 = (a1 / d0 + a3 / d1 + a5 / d2) * (1.f / 3.f) + bias2[1];
    *(float2*)(out + (size_t)n * 2) = make_float2(o0, o1);
  }
}

// ---------------------------------------------------------------------------
extern "C" void kernel_launch(void* const* d_in, const int* in_sizes, int n_in,
                              void* d_out, int out_size, void* d_ws, size_t ws_size,
                              hipStream_t stream) {
  const float* x        = (const float*)d_in[0];
  const int*   ei       = (const int*)d_in[1];
  const float* W1       = (const float*)d_in[2];
  const float* att_src1 = (const float*)d_in[3];
  const float* att_dst1 = (const float*)d_in[4];
  const float* bias1    = (const float*)d_in[5];
  const float* W2       = (const float*)d_in[6];
  const float* att_src2 = (const float*)d_in[7];
  const float* att_dst2 = (const float*)d_in[8];
  const float* bias2    = (const float*)d_in[9];
  float* out = (float*)d_out;

  char* w = (char*)d_ws;
  auto alloc = [&](size_t bytes) {
    char* p = w;
    w += (bytes + 255) & ~(size_t)255;
    return p;
  };
  unsigned short* h1u    = (unsigned short*)alloc((size_t)N_NODES * C_HID * 2);  // 12.8 MB
  unsigned short* Wswz   = (unsigned short*)alloc((size_t)C_IN * C_HID * 2 * 2); // 256 KB
  float*          v1s    = (float*)alloc((size_t)C_IN * 4);
  float*          v1d    = (float*)alloc((size_t)C_IN * 4);
  float*          a_src1 = (float*)alloc((size_t)N_NODES * 4);
  float*          a_dst1 = (float*)alloc((size_t)N_NODES * 4);
  int*            deg    = (int*)alloc((size_t)N_NODES * 4);
  int*            rowptr = (int*)alloc((size_t)(N_NODES + 4) * 4);
  int*            rnk    = (int*)alloc((size_t)N_EDGES * 4);                     // 3.2 MB
  int2*           esw    = (int2*)alloc((size_t)E_TOT * 8);                      // 6.8 MB
  float*          hs2    = (float*)alloc((size_t)N_NODES * 12 * 4);              // 2.4 MB

  (void)hipMemsetAsync(deg, 0, (size_t)N_NODES * 4, stream);

  setup_kernel<<<160 + (N_EDGES + 255) / 256, 256, 0, stream>>>(
      W1, att_src1, att_dst1, ei, Wswz, v1s, v1d, deg, rnk);
  // scan folded into lin1's block 0 (runs concurrent with the GEMM blocks)
  lin1_kernel<<<(N_NODES + 63) / 64 + 1, 256, 0, stream>>>(x, Wswz, v1s, v1d,
                                                           h1u, a_src1, a_dst1,
                                                           deg, rowptr);
  bucket_kernel<<<(E_TOT + 255) / 256, 256, 0, stream>>>(ei, rnk, rowptr,
                                                         a_src1, a_dst1, esw);
  agg1_kernel<<<(N_NODES / 2 + 15) / 16, 256, 0, stream>>>(h1u, esw, rowptr, bias1, W2,
                                                           att_src2, att_dst2, hs2);
  agg2_kernel<<<(N_NODES + 15) / 16, 256, 0, stream>>>(hs2, rowptr, esw, bias2, out);
}

// Round 7
// 291.918 us; speedup vs baseline: 1.0569x; 1.0330x over previous
//
#include <hip/hip_runtime.h>

#define N_NODES 50000
#define N_EDGES 800000
#define E_TOT   850000   /* N_EDGES + N_NODES self-loops */
#define C_IN    512
#define C_HID   128
#define NEG     0.2f

typedef _Float16 f16x8 __attribute__((ext_vector_type(8)));
typedef __attribute__((ext_vector_type(4))) float f32x4;

__device__ __forceinline__ float leaky(float x) { return x > 0.f ? x : NEG * x; }

union U32H2 { unsigned u; _Float16 h[2]; float f; };
union BFrag { uint4 u; f16x8 h; };

__device__ __forceinline__ unsigned short f2h(float f) {
  U32H2 c; c.h[0] = (_Float16)f; return (unsigned short)(c.u & 0xffff);
}

// pack two fp32 -> fp16x2 (RTZ hardware op) as raw u32
__device__ __forceinline__ unsigned pk2h(float a, float b) {
  union { __fp16 v __attribute__((ext_vector_type(2))); unsigned u; } c;
  c.v = __builtin_amdgcn_cvt_pkrtz(a, b);
  return c.u;
}

// Full 16-lane (DPP row) all-reduce add on the VALU pipe — zero DS ops.
// Stages: quad xor1, quad xor2, row_ror:4, row_ror:8.
__device__ __forceinline__ float row_reduce_add(float v) {
  union { float f; int i; } a, b;
  a.f = v;
  b.i = __builtin_amdgcn_update_dpp(0, a.i, 0xB1, 0xF, 0xF, true);  a.f += b.f;
  b.i = __builtin_amdgcn_update_dpp(0, a.i, 0x4E, 0xF, 0xF, true);  a.f += b.f;
  b.i = __builtin_amdgcn_update_dpp(0, a.i, 0x124, 0xF, 0xF, true); a.f += b.f;
  b.i = __builtin_amdgcn_update_dpp(0, a.i, 0x128, 0xF, 0xF, true); a.f += b.f;
  return a.f;
}

// ---------------------------------------------------------------------------
// setup: fuses prep_w (blocks 0..31), prep_v (32..159), deg+rank (160..3284).
// ---------------------------------------------------------------------------
__global__ __launch_bounds__(256) void setup_kernel(
    const float* __restrict__ W1, const float* __restrict__ as1,
    const float* __restrict__ ad1, const int* __restrict__ ei,
    unsigned short* __restrict__ Wswz, float* __restrict__ v1s, float* __restrict__ v1d,
    int* __restrict__ deg, int* __restrict__ rnk) {
  const int b = blockIdx.x;
  if (b < 32) {
    int t = b * 256 + threadIdx.x;                 // 8192 threads
    int c = t >> 6, kc = t & 63;
    if (c >= C_HID) return;
    int kblk = kc >> 2, q = kc & 3;
    int ct = c >> 4, l15 = c & 15;
    int lane = q * 16 + l15;
    unsigned short hb[8], lb[8];
#pragma unroll
    for (int i = 0; i < 8; i++) {
      float w = W1[(size_t)(kc * 8 + i) * C_HID + c];
      _Float16 hi = (_Float16)w;                   // RNE
      _Float16 lo = (_Float16)(w - (float)hi);
      U32H2 ch; ch.h[0] = hi;
      U32H2 cl; cl.h[0] = lo;
      hb[i] = (unsigned short)(ch.u & 0xffff);
      lb[i] = (unsigned short)(cl.u & 0xffff);
    }
    size_t chunk0 = ((size_t)(kblk * 8 + ct) * 2) * 512;
    *(uint4*)&Wswz[chunk0 + (size_t)lane * 8]       = *(uint4*)hb;
    *(uint4*)&Wswz[chunk0 + 512 + (size_t)lane * 8] = *(uint4*)lb;
  } else if (b < 160) {
    const int wv = threadIdx.x >> 6, lane = threadIdx.x & 63;
    const int k = (b - 32) * 4 + wv;
    if (k >= C_IN) return;
    float2 w = *(const float2*)(W1 + (size_t)k * C_HID + 2 * lane);
    float2 a = *(const float2*)(as1 + 2 * lane);
    float2 d = *(const float2*)(ad1 + 2 * lane);
    float s = w.x * a.x + w.y * a.y;
    float t = w.x * d.x + w.y * d.y;
#pragma unroll
    for (int m = 32; m >= 1; m >>= 1) {
      s += __shfl_xor(s, m, 64);
      t += __shfl_xor(t, m, 64);
    }
    if (lane == 0) { v1s[k] = s; v1d[k] = t; }
  } else {
    int e = (b - 160) * 256 + threadIdx.x;
    if (e < N_EDGES) rnk[e] = atomicAdd(&deg[ei[N_EDGES + e]], 1);
  }
}

// ---------------------------------------------------------------------------
// lin1: h1 = x @ W1 via fp16 MFMA (x_h*W_hi + x_h*W_lo), fused fp32 a_src/a_dst.
// Round-3 structure with K=64 PER BARRIER ROUND: 8 lock-stepped rounds instead
// of 16 (the round-latency chain, not bandwidth or MFMA, is the measured
// cost: MfmaUtil 7.8%, VALUBusy 6.6%). Per round a thread stages 16 floats
// (two 32-k sub-blocks), one __syncthreads, 8 B-frag loads (L2), 32 MFMAs.
// LDS 20.5 KB (2 buf x 2 sub x 64 x 40). Block 0 runs the rowptr scan.
// ---------------------------------------------------------------------------
__global__ __launch_bounds__(256) void lin1_kernel(const float* __restrict__ x,
    const unsigned short* __restrict__ Wswz,
    const float* __restrict__ v1s, const float* __restrict__ v1d,
    unsigned short* __restrict__ h1u, float* __restrict__ a_src, float* __restrict__ a_dst,
    const int* __restrict__ deg, int* __restrict__ rowptr) {
  __shared__ __attribute__((aligned(16))) unsigned short As[2][2][64][40];  // 20.5 KB
  __shared__ int wsum[4];

  if (blockIdx.x == 0) {
    // ---- scan block: exclusive prefix of (deg+1) over 50000 nodes ----
    const int tid = threadIdx.x, lane = tid & 63, wv = tid >> 6;
    int carry = 0;
    for (int base = 0; base < N_NODES; base += 8192) {
      int i0 = base + tid * 32;
      int v[32];
      if (i0 + 32 <= N_NODES) {
#pragma unroll
        for (int k = 0; k < 8; k++) {
          int4 t4 = *(const int4*)(deg + i0 + 4 * k);
          v[4 * k]     = t4.x + 1; v[4 * k + 1] = t4.y + 1;
          v[4 * k + 2] = t4.z + 1; v[4 * k + 3] = t4.w + 1;
        }
      } else {
#pragma unroll
        for (int k = 0; k < 32; k++) v[k] = (i0 + k < N_NODES) ? deg[i0 + k] + 1 : 0;
      }
      int tsum = 0;
#pragma unroll
      for (int k = 0; k < 32; k++) tsum += v[k];
      int sc = tsum;                                   // inclusive scan of thread sums
#pragma unroll
      for (int off = 1; off < 64; off <<= 1) {
        int t = __shfl_up(sc, off, 64);
        if (lane >= off) sc += t;
      }
      if (lane == 63) wsum[wv] = sc;
      __syncthreads();
      if (tid < 4) {
        int s = wsum[tid];
#pragma unroll
        for (int off = 1; off < 4; off <<= 1) {
          int t = __shfl_up(s, off, 64);
          if (tid >= off) s += t;
        }
        wsum[tid] = s;
      }
      __syncthreads();
      int run = carry + (wv ? wsum[wv - 1] : 0) + sc - tsum;   // exclusive base
      if (i0 + 32 <= N_NODES) {
#pragma unroll
        for (int k = 0; k < 8; k++) {
          int4 w4;
          w4.x = run; run += v[4 * k];
          w4.y = run; run += v[4 * k + 1];
          w4.z = run; run += v[4 * k + 2];
          w4.w = run; run += v[4 * k + 3];
          *(int4*)(rowptr + i0 + 4 * k) = w4;
        }
      } else {
#pragma unroll
        for (int k = 0; k < 32; k++) {
          if (i0 + k < N_NODES) rowptr[i0 + k] = run;
          run += v[k];
        }
      }
      carry += wsum[3];
      __syncthreads();
    }
    if (tid == 0) rowptr[N_NODES] = carry;
    return;
  }

  const int tid  = threadIdx.x;
  const int lane = tid & 63, wv = tid >> 6;
  const int m0   = (blockIdx.x - 1) * 64;

  const int arow = tid >> 2, kseg = (tid & 3) * 8;
  int grow = m0 + arow;
  if (grow >= N_NODES) grow = N_NODES - 1;          // clamp; stores guarded
  const float* xrow = x + (size_t)grow * C_IN + kseg;

  f32x4 acc[4][2];
#pragma unroll
  for (int rt = 0; rt < 4; rt++) { acc[rt][0] = (f32x4)0.f; acc[rt][1] = (f32x4)0.f; }
  float ps = 0.f, pd = 0.f;

  const int q = lane >> 4, l15 = lane & 15;

  // prefetch both sub-blocks of round 0
  float4 xa0 = *(const float4*)(xrow);
  float4 xb0 = *(const float4*)(xrow + 4);
  float4 xa1 = *(const float4*)(xrow + 32);
  float4 xb1 = *(const float4*)(xrow + 36);

#pragma unroll
  for (int kb = 0; kb < 8; kb++) {
    const int k0 = kb * 64;
    const int buf = kb & 1;
    {
      float4 vsa = *(const float4*)(v1s + k0 + kseg);
      float4 vsb = *(const float4*)(v1s + k0 + kseg + 4);
      float4 vda = *(const float4*)(v1d + k0 + kseg);
      float4 vdb = *(const float4*)(v1d + k0 + kseg + 4);
      ps += xa0.x * vsa.x + xa0.y * vsa.y + xa0.z * vsa.z + xa0.w * vsa.w
          + xb0.x * vsb.x + xb0.y * vsb.y + xb0.z * vsb.z + xb0.w * vsb.w;
      pd += xa0.x * vda.x + xa0.y * vda.y + xa0.z * vda.z + xa0.w * vda.w
          + xb0.x * vdb.x + xb0.y * vdb.y + xb0.z * vdb.z + xb0.w * vdb.w;
      float4 vsc = *(const float4*)(v1s + k0 + 32 + kseg);
      float4 vsd = *(const float4*)(v1s + k0 + 32 + kseg + 4);
      float4 vdc = *(const float4*)(v1d + k0 + 32 + kseg);
      float4 vdd = *(const float4*)(v1d + k0 + 32 + kseg + 4);
      ps += xa1.x * vsc.x + xa1.y * vsc.y + xa1.z * vsc.z + xa1.w * vsc.w
          + xb1.x * vsd.x + xb1.y * vsd.y + xb1.z * vsd.z + xb1.w * vsd.w;
      pd += xa1.x * vdc.x + xa1.y * vdc.y + xa1.z * vdc.z + xa1.w * vdc.w
          + xb1.x * vdd.x + xb1.y * vdd.y + xb1.z * vdd.z + xb1.w * vdd.w;
    }
    *(uint4*)&As[buf][0][arow][kseg] = make_uint4(pk2h(xa0.x, xa0.y), pk2h(xa0.z, xa0.w),
                                                  pk2h(xb0.x, xb0.y), pk2h(xb0.z, xb0.w));
    *(uint4*)&As[buf][1][arow][kseg] = make_uint4(pk2h(xa1.x, xa1.y), pk2h(xa1.z, xa1.w),
                                                  pk2h(xb1.x, xb1.y), pk2h(xb1.z, xb1.w));
    __syncthreads();                                // As[buf] ready
    if (kb < 7) {                                   // prefetch next round's x
      xa0 = *(const float4*)(xrow + k0 + 64);
      xb0 = *(const float4*)(xrow + k0 + 68);
      xa1 = *(const float4*)(xrow + k0 + 96);
      xb1 = *(const float4*)(xrow + k0 + 100);
    }

    // B fragments for both sub-blocks (8 x uint4, L2-resident), then MFMAs
    const unsigned short* bp0 = Wswz + ((size_t)((kb * 2) * 8 + wv * 2) * 2) * 512 + (size_t)lane * 8;
    const unsigned short* bp1 = Wswz + ((size_t)((kb * 2 + 1) * 8 + wv * 2) * 2) * 512 + (size_t)lane * 8;
    BFrag s0b00, s0b01, s0b10, s0b11, s1b00, s1b01, s1b10, s1b11;
    s0b00.u = *(const uint4*)(bp0);
    s0b01.u = *(const uint4*)(bp0 + 512);
    s0b10.u = *(const uint4*)(bp0 + 1024);
    s0b11.u = *(const uint4*)(bp0 + 1536);
    s1b00.u = *(const uint4*)(bp1);
    s1b01.u = *(const uint4*)(bp1 + 512);
    s1b10.u = *(const uint4*)(bp1 + 1024);
    s1b11.u = *(const uint4*)(bp1 + 1536);

#pragma unroll
    for (int rt = 0; rt < 4; rt++) {
      f16x8 af0 = *(const f16x8*)&As[buf][0][rt * 16 + l15][q * 8];
      acc[rt][0] = __builtin_amdgcn_mfma_f32_16x16x32_f16(af0, s0b00.h, acc[rt][0], 0, 0, 0);
      acc[rt][0] = __builtin_amdgcn_mfma_f32_16x16x32_f16(af0, s0b01.h, acc[rt][0], 0, 0, 0);
      acc[rt][1] = __builtin_amdgcn_mfma_f32_16x16x32_f16(af0, s0b10.h, acc[rt][1], 0, 0, 0);
      acc[rt][1] = __builtin_amdgcn_mfma_f32_16x16x32_f16(af0, s0b11.h, acc[rt][1], 0, 0, 0);
      f16x8 af1 = *(const f16x8*)&As[buf][1][rt * 16 + l15][q * 8];
      acc[rt][0] = __builtin_amdgcn_mfma_f32_16x16x32_f16(af1, s1b00.h, acc[rt][0], 0, 0, 0);
      acc[rt][0] = __builtin_amdgcn_mfma_f32_16x16x32_f16(af1, s1b01.h, acc[rt][0], 0, 0, 0);
      acc[rt][1] = __builtin_amdgcn_mfma_f32_16x16x32_f16(af1, s1b10.h, acc[rt][1], 0, 0, 0);
      acc[rt][1] = __builtin_amdgcn_mfma_f32_16x16x32_f16(af1, s1b11.h, acc[rt][1], 0, 0, 0);
    }
  }

  // attention dots: reduce over the 4 staging threads sharing a row
  ps += __shfl_xor(ps, 1, 64); ps += __shfl_xor(ps, 2, 64);
  pd += __shfl_xor(pd, 1, 64); pd += __shfl_xor(pd, 2, 64);
  if ((tid & 3) == 0) {
    int row = m0 + arow;
    if (row < N_NODES) { a_src[row] = ps; a_dst[row] = pd; }
  }

  // C store (fp16): C/D layout col=lane&15, row=(lane>>4)*4+reg
#pragma unroll
  for (int rt = 0; rt < 4; rt++) {
    int rbase = m0 + rt * 16 + q * 4;
#pragma unroll
    for (int ct = 0; ct < 2; ct++) {
      int col = wv * 32 + ct * 16 + l15;
#pragma unroll
      for (int ri = 0; ri < 4; ri++) {
        int row = rbase + ri;
        if (row < N_NODES)
          h1u[(size_t)row * C_HID + col] = f2h(acc[rt][ct][ri]);
      }
    }
  }
}

// ---------------------------------------------------------------------------
// bucket: no atomics. Edge e -> slot rowptr[dst]+rank[e]; self-loop n -> slot
// rowptr[n+1]-1. Weight w = exp(leaky(a_src+a_dst)) fused in.
// ---------------------------------------------------------------------------
__global__ void bucket_kernel(const int* __restrict__ ei, const int* __restrict__ rnk,
                              const int* __restrict__ rowptr,
                              const float* __restrict__ a_src, const float* __restrict__ a_dst,
                              int2* __restrict__ esw) {
  int e = blockIdx.x * blockDim.x + threadIdx.x;
  if (e >= E_TOT) return;
  int src, slot;
  if (e < N_EDGES) {
    src = ei[e];
    int dst = ei[N_EDGES + e];
    slot = rowptr[dst] + rnk[e];
    U32H2 c; c.f = __expf(leaky(a_src[src] + a_dst[dst]));
    esw[slot] = make_int2(src, (int)c.u);
  } else {
    int n = e - N_EDGES;
    slot = rowptr[n + 1] - 1;
    U32H2 c; c.f = __expf(leaky(a_src[n] + a_dst[n]));
    esw[slot] = make_int2(n, (int)c.u);
  }
}

// ---------------------------------------------------------------------------
// agg1: 16 lanes per node (4 nodes/wave), lane r owns channels r*8..r*8+7.
// ZERO DS ops (broadcast rec loads, DPP epilogue). Per 8-edge round the chain
// was rec-load -> gather -> FMA (two serial latencies); the NEXT round's 8
// records are now prefetched (+16 VGPR double-buffer) while the current
// round's gathers/FMAs run, removing one latency per round. Padded slots
// clamp to the bucket's first record with w=0.
// hs2[n] = {p0..p5, as0..as2, ad0..ad2}.
// ---------------------------------------------------------------------------
__global__ __launch_bounds__(256) void agg1_kernel(const unsigned short* __restrict__ h1u,
    const int2* __restrict__ esw, const int* __restrict__ rowptr,
    const float* __restrict__ bias1, const float* __restrict__ W2,
    const float* __restrict__ as2w, const float* __restrict__ ad2w,
    float* __restrict__ hs2) {
  const int wv = threadIdx.x >> 6, lane = threadIdx.x & 63;
  const int r = lane & 15;
  const int n = blockIdx.x * 16 + wv * 4 + (lane >> 4);   // grid covers N exactly
  const int start = rowptr[n], end = rowptr[n + 1];

  const unsigned short* hbase = h1u + r * 8;

  float acc[8] = {0, 0, 0, 0, 0, 0, 0, 0};
  float wsum = 0.f;

  int base = start;
  int cnt = min(end - base, 8);
  int2 rec[8];
#pragma unroll
  for (int j = 0; j < 8; j++) rec[j] = esw[j < cnt ? base + j : base];

  while (true) {
    const int nbase = base + 8;
    const bool more = nbase < end;                 // group-uniform
    int ncnt = 0;
    int2 nrec[8];
    if (more) {                                    // prefetch next round's records
      ncnt = min(end - nbase, 8);
#pragma unroll
      for (int j = 0; j < 8; j++) nrec[j] = esw[j < ncnt ? nbase + j : nbase];
    }
    uint4 g[8];
#pragma unroll
    for (int j = 0; j < 8; j++)
      g[j] = *(const uint4*)(hbase + (size_t)rec[j].x * C_HID);
#pragma unroll
    for (int j = 0; j < 8; j++) {
      U32H2 cw; cw.u = (unsigned)rec[j].y;
      const float W = (j < cnt) ? cw.f : 0.f;
      wsum += W;
      U32H2 c0, c1, c2, c3;
      c0.u = g[j].x; c1.u = g[j].y; c2.u = g[j].z; c3.u = g[j].w;
      acc[0] = fmaf(W, (float)c0.h[0], acc[0]); acc[1] = fmaf(W, (float)c0.h[1], acc[1]);
      acc[2] = fmaf(W, (float)c1.h[0], acc[2]); acc[3] = fmaf(W, (float)c1.h[1], acc[3]);
      acc[4] = fmaf(W, (float)c2.h[0], acc[4]); acc[5] = fmaf(W, (float)c2.h[1], acc[5]);
      acc[6] = fmaf(W, (float)c3.h[0], acc[6]); acc[7] = fmaf(W, (float)c3.h[1], acc[7]);
    }
    if (!more) break;
    base = nbase; cnt = ncnt;
#pragma unroll
    for (int j = 0; j < 8; j++) rec[j] = nrec[j];
  }

  const float inv = 1.f / wsum;                    // > 0 via self-loop; uniform in group

  float4 ba = *(const float4*)(bias1 + r * 8);
  float4 bb = *(const float4*)(bias1 + r * 8 + 4);
  float u[8] = {fmaxf(acc[0] * inv + ba.x, 0.f), fmaxf(acc[1] * inv + ba.y, 0.f),
                fmaxf(acc[2] * inv + ba.z, 0.f), fmaxf(acc[3] * inv + ba.w, 0.f),
                fmaxf(acc[4] * inv + bb.x, 0.f), fmaxf(acc[5] * inv + bb.y, 0.f),
                fmaxf(acc[6] * inv + bb.z, 0.f), fmaxf(acc[7] * inv + bb.w, 0.f)};
  float p[6] = {0, 0, 0, 0, 0, 0};
#pragma unroll
  for (int j = 0; j < 8; j++) {
    const float* w2r = W2 + (size_t)(r * 8 + j) * 6;   // L1-hot (3 KB total)
#pragma unroll
    for (int o = 0; o < 6; o++) p[o] = fmaf(u[j], w2r[o], p[o]);
  }
  // fold over the 16 lanes of the group — DPP, zero DS ops
#pragma unroll
  for (int o = 0; o < 6; o++) p[o] = row_reduce_add(p[o]);

  if (r == 0) {
    float as0 = p[0] * as2w[0] + p[1] * as2w[1];
    float as1 = p[2] * as2w[2] + p[3] * as2w[3];
    float as2_ = p[4] * as2w[4] + p[5] * as2w[5];
    float ad0 = p[0] * ad2w[0] + p[1] * ad2w[1];
    float ad1 = p[2] * ad2w[2] + p[3] * ad2w[3];
    float ad2_ = p[4] * ad2w[4] + p[5] * ad2w[5];
    float* dst = hs2 + (size_t)n * 12;
    *(float4*)(dst)     = make_float4(p[0], p[1], p[2], p[3]);
    *(float4*)(dst + 4) = make_float4(p[4], p[5], as0, as1);
    *(float4*)(dst + 8) = make_float4(as2_, ad0, ad1, ad2_);
  }
}

// ---------------------------------------------------------------------------
// agg2: 16 lanes per node (4 nodes/wave); per edge ONE 48-B packed record
// {p0..p5, as0..as2} (3 loads, 1-2 lines). Folds via DPP row reduction.
// out = mean over heads + bias2.
// ---------------------------------------------------------------------------
__global__ __launch_bounds__(256) void agg2_kernel(const float* __restrict__ hs2,
    const int* __restrict__ rowptr, const int2* __restrict__ esw,
    const float* __restrict__ bias2, float* __restrict__ out) {
  const int wv = threadIdx.x >> 6, lane = threadIdx.x & 63;
  const int q = lane >> 4, r = lane & 15;
  const int n = blockIdx.x * 16 + wv * 4 + q;
  if (n >= N_NODES) return;
  const int start = rowptr[n], end = rowptr[n + 1];
  float4 own = *(const float4*)(hs2 + (size_t)n * 12 + 8);   // {as2, ad0, ad1, ad2}
  const float ad0 = own.y, ad1 = own.z, ad2 = own.w;

  float d0 = 0.f, d1 = 0.f, d2 = 0.f;
  float a0 = 0.f, a1 = 0.f, a2 = 0.f, a3 = 0.f, a4 = 0.f, a5 = 0.f;
  for (int j = start + r; j < end; j += 16) {
    int s = esw[j].x;
    const float* rec = hs2 + (size_t)s * 12;
    float4 A = *(const float4*)(rec);          // p0..p3
    float4 B = *(const float4*)(rec + 4);      // p4, p5, as0, as1
    float  C = rec[8];                         // as2
    float e0 = __expf(leaky(B.z + ad0));
    float e1 = __expf(leaky(B.w + ad1));
    float e2 = __expf(leaky(C + ad2));
    d0 += e0; d1 += e1; d2 += e2;
    a0 += e0 * A.x; a1 += e0 * A.y;
    a2 += e1 * A.z; a3 += e1 * A.w;
    a4 += e2 * B.x; a5 += e2 * B.y;
  }
  d0 = row_reduce_add(d0); d1 = row_reduce_add(d1); d2 = row_reduce_add(d2);
  a0 = row_reduce_add(a0); a1 = row_reduce_add(a1); a2 = row_reduce_add(a2);
  a3 = row_reduce_add(a3); a4 = row_reduce_add(a4); a5 = row_reduce_add(a5);
  if (r == 0) {
    float o0 = (a0 / d0 + a2 / d1 + a4 / d2) * (1.f / 3.f) + bias2[0];
    float o1 = (a1 / d0 + a3 / d1 + a5 / d2) * (1.f / 3.f) + bias2[1];
    *(float2*)(out + (size_t)n * 2) = make_float2(o0, o1);
  }
}

// ---------------------------------------------------------------------------
extern "C" void kernel_launch(void* const* d_in, const int* in_sizes, int n_in,
                              void* d_out, int out_size, void* d_ws, size_t ws_size,
                              hipStream_t stream) {
  const float* x        = (const float*)d_in[0];
  const int*   ei       = (const int*)d_in[1];
  const float* W1       = (const float*)d_in[2];
  const float* att_src1 = (const float*)d_in[3];
  const float* att_dst1 = (const float*)d_in[4];
  const float* bias1    = (const float*)d_in[5];
  const float* W2       = (const float*)d_in[6];
  const float* att_src2 = (const float*)d_in[7];
  const float* att_dst2 = (const float*)d_in[8];
  const float* bias2    = (const float*)d_in[9];
  float* out = (float*)d_out;

  char* w = (char*)d_ws;
  auto alloc = [&](size_t bytes) {
    char* p = w;
    w += (bytes + 255) & ~(size_t)255;
    return p;
  };
  unsigned short* h1u    = (unsigned short*)alloc((size_t)N_NODES * C_HID * 2);  // 12.8 MB
  unsigned short* Wswz   = (unsigned short*)alloc((size_t)C_IN * C_HID * 2 * 2); // 256 KB
  float*          v1s    = (float*)alloc((size_t)C_IN * 4);
  float*          v1d    = (float*)alloc((size_t)C_IN * 4);
  float*          a_src1 = (float*)alloc((size_t)N_NODES * 4);
  float*          a_dst1 = (float*)alloc((size_t)N_NODES * 4);
  int*            deg    = (int*)alloc((size_t)N_NODES * 4);
  int*            rowptr = (int*)alloc((size_t)(N_NODES + 4) * 4);
  int*            rnk    = (int*)alloc((size_t)N_EDGES * 4);                     // 3.2 MB
  int2*           esw    = (int2*)alloc((size_t)E_TOT * 8);                      // 6.8 MB
  float*          hs2    = (float*)alloc((size_t)N_NODES * 12 * 4);              // 2.4 MB

  (void)hipMemsetAsync(deg, 0, (size_t)N_NODES * 4, stream);

  setup_kernel<<<160 + (N_EDGES + 255) / 256, 256, 0, stream>>>(
      W1, att_src1, att_dst1, ei, Wswz, v1s, v1d, deg, rnk);
  // scan folded into lin1's block 0 (runs concurrent with the GEMM blocks)
  lin1_kernel<<<(N_NODES + 63) / 64 + 1, 256, 0, stream>>>(x, Wswz, v1s, v1d,
                                                           h1u, a_src1, a_dst1,
                                                           deg, rowptr);
  bucket_kernel<<<(E_TOT + 255) / 256, 256, 0, stream>>>(ei, rnk, rowptr,
                                                         a_src1, a_dst1, esw);
  agg1_kernel<<<N_NODES / 16, 256, 0, stream>>>(h1u, esw, rowptr, bias1, W2,
                                                att_src2, att_dst2, hs2);
  agg2_kernel<<<(N_NODES + 15) / 16, 256, 0, stream>>>(hs2, rowptr, esw, bias2, out);
}

// Round 8
// 290.350 us; speedup vs baseline: 1.0626x; 1.0054x over previous
//
#include <hip/hip_runtime.h>

#define N_NODES 50000
#define N_EDGES 800000
#define E_TOT   850000   /* N_EDGES + N_NODES self-loops */
#define C_IN    512
#define C_HID   128
#define NEG     0.2f

typedef _Float16 f16x8 __attribute__((ext_vector_type(8)));
typedef __attribute__((ext_vector_type(4))) float f32x4;

__device__ __forceinline__ float leaky(float x) { return x > 0.f ? x : NEG * x; }

union U32H2 { unsigned u; _Float16 h[2]; float f; };
union BFrag { uint4 u; f16x8 h; };

__device__ __forceinline__ unsigned short f2h(float f) {
  U32H2 c; c.h[0] = (_Float16)f; return (unsigned short)(c.u & 0xffff);
}

// pack two fp32 -> fp16x2 (RTZ hardware op) as raw u32
__device__ __forceinline__ unsigned pk2h(float a, float b) {
  union { __fp16 v __attribute__((ext_vector_type(2))); unsigned u; } c;
  c.v = __builtin_amdgcn_cvt_pkrtz(a, b);
  return c.u;
}

// Full 16-lane (DPP row) all-reduce add on the VALU pipe — zero DS ops.
// Stages: quad xor1, quad xor2, row_ror:4, row_ror:8.
__device__ __forceinline__ float row_reduce_add(float v) {
  union { float f; int i; } a, b;
  a.f = v;
  b.i = __builtin_amdgcn_update_dpp(0, a.i, 0xB1, 0xF, 0xF, true);  a.f += b.f;
  b.i = __builtin_amdgcn_update_dpp(0, a.i, 0x4E, 0xF, 0xF, true);  a.f += b.f;
  b.i = __builtin_amdgcn_update_dpp(0, a.i, 0x124, 0xF, 0xF, true); a.f += b.f;
  b.i = __builtin_amdgcn_update_dpp(0, a.i, 0x128, 0xF, 0xF, true); a.f += b.f;
  return a.f;
}

// ---------------------------------------------------------------------------
// setup: fuses prep_w (blocks 0..31), prep_v (32..159), deg+rank (160..3284).
// ---------------------------------------------------------------------------
__global__ __launch_bounds__(256) void setup_kernel(
    const float* __restrict__ W1, const float* __restrict__ as1,
    const float* __restrict__ ad1, const int* __restrict__ ei,
    unsigned short* __restrict__ Wswz, float* __restrict__ v1s, float* __restrict__ v1d,
    int* __restrict__ deg, int* __restrict__ rnk) {
  const int b = blockIdx.x;
  if (b < 32) {
    int t = b * 256 + threadIdx.x;                 // 8192 threads
    int c = t >> 6, kc = t & 63;
    if (c >= C_HID) return;
    int kblk = kc >> 2, q = kc & 3;
    int ct = c >> 4, l15 = c & 15;
    int lane = q * 16 + l15;
    unsigned short hb[8], lb[8];
#pragma unroll
    for (int i = 0; i < 8; i++) {
      float w = W1[(size_t)(kc * 8 + i) * C_HID + c];
      _Float16 hi = (_Float16)w;                   // RNE
      _Float16 lo = (_Float16)(w - (float)hi);
      U32H2 ch; ch.h[0] = hi;
      U32H2 cl; cl.h[0] = lo;
      hb[i] = (unsigned short)(ch.u & 0xffff);
      lb[i] = (unsigned short)(cl.u & 0xffff);
    }
    size_t chunk0 = ((size_t)(kblk * 8 + ct) * 2) * 512;
    *(uint4*)&Wswz[chunk0 + (size_t)lane * 8]       = *(uint4*)hb;
    *(uint4*)&Wswz[chunk0 + 512 + (size_t)lane * 8] = *(uint4*)lb;
  } else if (b < 160) {
    const int wv = threadIdx.x >> 6, lane = threadIdx.x & 63;
    const int k = (b - 32) * 4 + wv;
    if (k >= C_IN) return;
    float2 w = *(const float2*)(W1 + (size_t)k * C_HID + 2 * lane);
    float2 a = *(const float2*)(as1 + 2 * lane);
    float2 d = *(const float2*)(ad1 + 2 * lane);
    float s = w.x * a.x + w.y * a.y;
    float t = w.x * d.x + w.y * d.y;
#pragma unroll
    for (int m = 32; m >= 1; m >>= 1) {
      s += __shfl_xor(s, m, 64);
      t += __shfl_xor(t, m, 64);
    }
    if (lane == 0) { v1s[k] = s; v1d[k] = t; }
  } else {
    int e = (b - 160) * 256 + threadIdx.x;
    if (e < N_EDGES) rnk[e] = atomicAdd(&deg[ei[N_EDGES + e]], 1);
  }
}

// ---------------------------------------------------------------------------
// lin1: h1 = x @ W1 via fp16 MFMA (x_h*W_hi + x_h*W_lo), fused fp32 a_src/a_dst.
// K=128 PER BARRIER ROUND: 4 lock-stepped rounds (validated model:
// T ~ N_rounds x round_latency + floor; 16->61us, 8->52us). Per round a
// thread stages 64 B (4 sub-k blocks), ONE barrier, B-frags loaded in two
// pairs of 8 (pair1 loads overlap pair0 MFMAs), 64 MFMAs. LDS 40 KB =
// 3 blocks/CU (matches the 3.05 blocks/CU grid). __launch_bounds__(256,3)
// pins 3 waves/SIMD so VGPR can't cut residency. Block 0 runs the rowptr
// scan (hidden under the GEMM blocks).
// ---------------------------------------------------------------------------
__global__ __launch_bounds__(256, 3) void lin1_kernel(const float* __restrict__ x,
    const unsigned short* __restrict__ Wswz,
    const float* __restrict__ v1s, const float* __restrict__ v1d,
    unsigned short* __restrict__ h1u, float* __restrict__ a_src, float* __restrict__ a_dst,
    const int* __restrict__ deg, int* __restrict__ rowptr) {
  __shared__ __attribute__((aligned(16))) unsigned short As[2][4][64][40];  // 40 KB
  __shared__ int wsum[4];

  if (blockIdx.x == 0) {
    // ---- scan block: exclusive prefix of (deg+1) over 50000 nodes ----
    const int tid = threadIdx.x, lane = tid & 63, wv = tid >> 6;
    int carry = 0;
    for (int base = 0; base < N_NODES; base += 8192) {
      int i0 = base + tid * 32;
      int v[32];
      if (i0 + 32 <= N_NODES) {
#pragma unroll
        for (int k = 0; k < 8; k++) {
          int4 t4 = *(const int4*)(deg + i0 + 4 * k);
          v[4 * k]     = t4.x + 1; v[4 * k + 1] = t4.y + 1;
          v[4 * k + 2] = t4.z + 1; v[4 * k + 3] = t4.w + 1;
        }
      } else {
#pragma unroll
        for (int k = 0; k < 32; k++) v[k] = (i0 + k < N_NODES) ? deg[i0 + k] + 1 : 0;
      }
      int tsum = 0;
#pragma unroll
      for (int k = 0; k < 32; k++) tsum += v[k];
      int sc = tsum;                                   // inclusive scan of thread sums
#pragma unroll
      for (int off = 1; off < 64; off <<= 1) {
        int t = __shfl_up(sc, off, 64);
        if (lane >= off) sc += t;
      }
      if (lane == 63) wsum[wv] = sc;
      __syncthreads();
      if (tid < 4) {
        int s = wsum[tid];
#pragma unroll
        for (int off = 1; off < 4; off <<= 1) {
          int t = __shfl_up(s, off, 64);
          if (tid >= off) s += t;
        }
        wsum[tid] = s;
      }
      __syncthreads();
      int run = carry + (wv ? wsum[wv - 1] : 0) + sc - tsum;   // exclusive base
      if (i0 + 32 <= N_NODES) {
#pragma unroll
        for (int k = 0; k < 8; k++) {
          int4 w4;
          w4.x = run; run += v[4 * k];
          w4.y = run; run += v[4 * k + 1];
          w4.z = run; run += v[4 * k + 2];
          w4.w = run; run += v[4 * k + 3];
          *(int4*)(rowptr + i0 + 4 * k) = w4;
        }
      } else {
#pragma unroll
        for (int k = 0; k < 32; k++) {
          if (i0 + k < N_NODES) rowptr[i0 + k] = run;
          run += v[k];
        }
      }
      carry += wsum[3];
      __syncthreads();
    }
    if (tid == 0) rowptr[N_NODES] = carry;
    return;
  }

  const int tid  = threadIdx.x;
  const int lane = tid & 63, wv = tid >> 6;
  const int m0   = (blockIdx.x - 1) * 64;

  const int arow = tid >> 2, kseg = (tid & 3) * 8;
  int grow = m0 + arow;
  if (grow >= N_NODES) grow = N_NODES - 1;          // clamp; stores guarded
  const float* xrow = x + (size_t)grow * C_IN + kseg;

  f32x4 acc[4][2];
#pragma unroll
  for (int rt = 0; rt < 4; rt++) { acc[rt][0] = (f32x4)0.f; acc[rt][1] = (f32x4)0.f; }
  float ps = 0.f, pd = 0.f;

  const int q = lane >> 4, l15 = lane & 15;

  // prefetch all 4 sub-blocks of round 0
  float4 xp[4][2];
#pragma unroll
  for (int s = 0; s < 4; s++) {
    xp[s][0] = *(const float4*)(xrow + s * 32);
    xp[s][1] = *(const float4*)(xrow + s * 32 + 4);
  }

#pragma unroll
  for (int kb = 0; kb < 4; kb++) {
    const int k0 = kb * 128;
    const int buf = kb & 1;
    // attention dot partials + LDS staging for the 4 sub-blocks
#pragma unroll
    for (int s = 0; s < 4; s++) {
      float4 vsa = *(const float4*)(v1s + k0 + s * 32 + kseg);
      float4 vsb = *(const float4*)(v1s + k0 + s * 32 + kseg + 4);
      float4 vda = *(const float4*)(v1d + k0 + s * 32 + kseg);
      float4 vdb = *(const float4*)(v1d + k0 + s * 32 + kseg + 4);
      ps += xp[s][0].x * vsa.x + xp[s][0].y * vsa.y + xp[s][0].z * vsa.z + xp[s][0].w * vsa.w
          + xp[s][1].x * vsb.x + xp[s][1].y * vsb.y + xp[s][1].z * vsb.z + xp[s][1].w * vsb.w;
      pd += xp[s][0].x * vda.x + xp[s][0].y * vda.y + xp[s][0].z * vda.z + xp[s][0].w * vda.w
          + xp[s][1].x * vdb.x + xp[s][1].y * vdb.y + xp[s][1].z * vdb.z + xp[s][1].w * vdb.w;
      *(uint4*)&As[buf][s][arow][kseg] =
          make_uint4(pk2h(xp[s][0].x, xp[s][0].y), pk2h(xp[s][0].z, xp[s][0].w),
                     pk2h(xp[s][1].x, xp[s][1].y), pk2h(xp[s][1].z, xp[s][1].w));
    }
    __syncthreads();                                // As[buf] ready
    if (kb < 3) {                                   // prefetch next round's x
#pragma unroll
      for (int s = 0; s < 4; s++) {
        xp[s][0] = *(const float4*)(xrow + k0 + 128 + s * 32);
        xp[s][1] = *(const float4*)(xrow + k0 + 128 + s * 32 + 4);
      }
    }

    // B-frags in two pairs of 8 (pair1 loads overlap pair0 MFMAs)
#pragma unroll
    for (int sp = 0; sp < 2; sp++) {
      BFrag bf[2][4];
#pragma unroll
      for (int s = 0; s < 2; s++) {
        const int sub = sp * 2 + s;
        const unsigned short* bp =
            Wswz + ((size_t)((kb * 4 + sub) * 8 + wv * 2) * 2) * 512 + (size_t)lane * 8;
        bf[s][0].u = *(const uint4*)(bp);
        bf[s][1].u = *(const uint4*)(bp + 512);
        bf[s][2].u = *(const uint4*)(bp + 1024);
        bf[s][3].u = *(const uint4*)(bp + 1536);
      }
#pragma unroll
      for (int rt = 0; rt < 4; rt++) {
#pragma unroll
        for (int s = 0; s < 2; s++) {
          const int sub = sp * 2 + s;
          f16x8 af = *(const f16x8*)&As[buf][sub][rt * 16 + l15][q * 8];
          acc[rt][0] = __builtin_amdgcn_mfma_f32_16x16x32_f16(af, bf[s][0].h, acc[rt][0], 0, 0, 0);
          acc[rt][0] = __builtin_amdgcn_mfma_f32_16x16x32_f16(af, bf[s][1].h, acc[rt][0], 0, 0, 0);
          acc[rt][1] = __builtin_amdgcn_mfma_f32_16x16x32_f16(af, bf[s][2].h, acc[rt][1], 0, 0, 0);
          acc[rt][1] = __builtin_amdgcn_mfma_f32_16x16x32_f16(af, bf[s][3].h, acc[rt][1], 0, 0, 0);
        }
      }
    }
  }

  // attention dots: reduce over the 4 staging threads sharing a row
  ps += __shfl_xor(ps, 1, 64); ps += __shfl_xor(ps, 2, 64);
  pd += __shfl_xor(pd, 1, 64); pd += __shfl_xor(pd, 2, 64);
  if ((tid & 3) == 0) {
    int row = m0 + arow;
    if (row < N_NODES) { a_src[row] = ps; a_dst[row] = pd; }
  }

  // C store (fp16): C/D layout col=lane&15, row=(lane>>4)*4+reg
#pragma unroll
  for (int rt = 0; rt < 4; rt++) {
    int rbase = m0 + rt * 16 + q * 4;
#pragma unroll
    for (int ct = 0; ct < 2; ct++) {
      int col = wv * 32 + ct * 16 + l15;
#pragma unroll
      for (int ri = 0; ri < 4; ri++) {
        int row = rbase + ri;
        if (row < N_NODES)
          h1u[(size_t)row * C_HID + col] = f2h(acc[rt][ct][ri]);
      }
    }
  }
}

// ---------------------------------------------------------------------------
// bucket: no atomics. Edge e -> slot rowptr[dst]+rank[e]; self-loop n -> slot
// rowptr[n+1]-1. Weight w = exp(leaky(a_src+a_dst)) fused in.
// ---------------------------------------------------------------------------
__global__ void bucket_kernel(const int* __restrict__ ei, const int* __restrict__ rnk,
                              const int* __restrict__ rowptr,
                              const float* __restrict__ a_src, const float* __restrict__ a_dst,
                              int2* __restrict__ esw) {
  int e = blockIdx.x * blockDim.x + threadIdx.x;
  if (e >= E_TOT) return;
  int src, slot;
  if (e < N_EDGES) {
    src = ei[e];
    int dst = ei[N_EDGES + e];
    slot = rowptr[dst] + rnk[e];
    U32H2 c; c.f = __expf(leaky(a_src[src] + a_dst[dst]));
    esw[slot] = make_int2(src, (int)c.u);
  } else {
    int n = e - N_EDGES;
    slot = rowptr[n + 1] - 1;
    U32H2 c; c.f = __expf(leaky(a_src[n] + a_dst[n]));
    esw[slot] = make_int2(n, (int)c.u);
  }
}

// ---------------------------------------------------------------------------
// agg1: 16 lanes per node (4 nodes/wave), lane r owns channels r*8..r*8+7.
// ZERO DS ops (broadcast rec loads, DPP epilogue). Per 8-edge round the chain
// was rec-load -> gather -> FMA (two serial latencies); the NEXT round's 8
// records are prefetched (+16 VGPR double-buffer) while the current round's
// gathers/FMAs run, removing one latency per round. Padded slots clamp to
// the bucket's first record with w=0. hs2[n] = {p0..p5, as0..as2, ad0..ad2}.
// ---------------------------------------------------------------------------
__global__ __launch_bounds__(256) void agg1_kernel(const unsigned short* __restrict__ h1u,
    const int2* __restrict__ esw, const int* __restrict__ rowptr,
    const float* __restrict__ bias1, const float* __restrict__ W2,
    const float* __restrict__ as2w, const float* __restrict__ ad2w,
    float* __restrict__ hs2) {
  const int wv = threadIdx.x >> 6, lane = threadIdx.x & 63;
  const int r = lane & 15;
  const int n = blockIdx.x * 16 + wv * 4 + (lane >> 4);   // grid covers N exactly
  const int start = rowptr[n], end = rowptr[n + 1];

  const unsigned short* hbase = h1u + r * 8;

  float acc[8] = {0, 0, 0, 0, 0, 0, 0, 0};
  float wsum = 0.f;

  int base = start;
  int cnt = min(end - base, 8);
  int2 rec[8];
#pragma unroll
  for (int j = 0; j < 8; j++) rec[j] = esw[j < cnt ? base + j : base];

  while (true) {
    const int nbase = base + 8;
    const bool more = nbase < end;                 // group-uniform
    int ncnt = 0;
    int2 nrec[8];
    if (more) {                                    // prefetch next round's records
      ncnt = min(end - nbase, 8);
#pragma unroll
      for (int j = 0; j < 8; j++) nrec[j] = esw[j < ncnt ? nbase + j : nbase];
    }
    uint4 g[8];
#pragma unroll
    for (int j = 0; j < 8; j++)
      g[j] = *(const uint4*)(hbase + (size_t)rec[j].x * C_HID);
#pragma unroll
    for (int j = 0; j < 8; j++) {
      U32H2 cw; cw.u = (unsigned)rec[j].y;
      const float W = (j < cnt) ? cw.f : 0.f;
      wsum += W;
      U32H2 c0, c1, c2, c3;
      c0.u = g[j].x; c1.u = g[j].y; c2.u = g[j].z; c3.u = g[j].w;
      acc[0] = fmaf(W, (float)c0.h[0], acc[0]); acc[1] = fmaf(W, (float)c0.h[1], acc[1]);
      acc[2] = fmaf(W, (float)c1.h[0], acc[2]); acc[3] = fmaf(W, (float)c1.h[1], acc[3]);
      acc[4] = fmaf(W, (float)c2.h[0], acc[4]); acc[5] = fmaf(W, (float)c2.h[1], acc[5]);
      acc[6] = fmaf(W, (float)c3.h[0], acc[6]); acc[7] = fmaf(W, (float)c3.h[1], acc[7]);
    }
    if (!more) break;
    base = nbase; cnt = ncnt;
#pragma unroll
    for (int j = 0; j < 8; j++) rec[j] = nrec[j];
  }

  const float inv = 1.f / wsum;                    // > 0 via self-loop; uniform in group

  float4 ba = *(const float4*)(bias1 + r * 8);
  float4 bb = *(const float4*)(bias1 + r * 8 + 4);
  float u[8] = {fmaxf(acc[0] * inv + ba.x, 0.f), fmaxf(acc[1] * inv + ba.y, 0.f),
                fmaxf(acc[2] * inv + ba.z, 0.f), fmaxf(acc[3] * inv + ba.w, 0.f),
                fmaxf(acc[4] * inv + bb.x, 0.f), fmaxf(acc[5] * inv + bb.y, 0.f),
                fmaxf(acc[6] * inv + bb.z, 0.f), fmaxf(acc[7] * inv + bb.w, 0.f)};
  float p[6] = {0, 0, 0, 0, 0, 0};
#pragma unroll
  for (int j = 0; j < 8; j++) {
    const float* w2r = W2 + (size_t)(r * 8 + j) * 6;   // L1-hot (3 KB total)
#pragma unroll
    for (int o = 0; o < 6; o++) p[o] = fmaf(u[j], w2r[o], p[o]);
  }
  // fold over the 16 lanes of the group — DPP, zero DS ops
#pragma unroll
  for (int o = 0; o < 6; o++) p[o] = row_reduce_add(p[o]);

  if (r == 0) {
    float as0 = p[0] * as2w[0] + p[1] * as2w[1];
    float as1 = p[2] * as2w[2] + p[3] * as2w[3];
    float as2_ = p[4] * as2w[4] + p[5] * as2w[5];
    float ad0 = p[0] * ad2w[0] + p[1] * ad2w[1];
    float ad1 = p[2] * ad2w[2] + p[3] * ad2w[3];
    float ad2_ = p[4] * ad2w[4] + p[5] * ad2w[5];
    float* dst = hs2 + (size_t)n * 12;
    *(float4*)(dst)     = make_float4(p[0], p[1], p[2], p[3]);
    *(float4*)(dst + 4) = make_float4(p[4], p[5], as0, as1);
    *(float4*)(dst + 8) = make_float4(as2_, ad0, ad1, ad2_);
  }
}

// ---------------------------------------------------------------------------
// agg2: 16 lanes per node (4 nodes/wave); per edge ONE 48-B packed record
// {p0..p5, as0..as2} (3 loads, 1-2 lines). Folds via DPP row reduction.
// out = mean over heads + bias2.
// ---------------------------------------------------------------------------
__global__ __launch_bounds__(256) void agg2_kernel(const float* __restrict__ hs2,
    const int* __restrict__ rowptr, const int2* __restrict__ esw,
    const float* __restrict__ bias2, float* __restrict__ out) {
  const int wv = threadIdx.x >> 6, lane = threadIdx.x & 63;
  const int q = lane >> 4, r = lane & 15;
  const int n = blockIdx.x * 16 + wv * 4 + q;
  if (n >= N_NODES) return;
  const int start = rowptr[n], end = rowptr[n + 1];
  float4 own = *(const float4*)(hs2 + (size_t)n * 12 + 8);   // {as2, ad0, ad1, ad2}
  const float ad0 = own.y, ad1 = own.z, ad2 = own.w;

  float d0 = 0.f, d1 = 0.f, d2 = 0.f;
  float a0 = 0.f, a1 = 0.f, a2 = 0.f, a3 = 0.f, a4 = 0.f, a5 = 0.f;
  for (int j = start + r; j < end; j += 16) {
    int s = esw[j].x;
    const float* rec = hs2 + (size_t)s * 12;
    float4 A = *(const float4*)(rec);          // p0..p3
    float4 B = *(const float4*)(rec + 4);      // p4, p5, as0, as1
    float  C = rec[8];                         // as2
    float e0 = __expf(leaky(B.z + ad0));
    float e1 = __expf(leaky(B.w + ad1));
    float e2 = __expf(leaky(C + ad2));
    d0 += e0; d1 += e1; d2 += e2;
    a0 += e0 * A.x; a1 += e0 * A.y;
    a2 += e1 * A.z; a3 += e1 * A.w;
    a4 += e2 * B.x; a5 += e2 * B.y;
  }
  d0 = row_reduce_add(d0); d1 = row_reduce_add(d1); d2 = row_reduce_add(d2);
  a0 = row_reduce_add(a0); a1 = row_reduce_add(a1); a2 = row_reduce_add(a2);
  a3 = row_reduce_add(a3); a4 = row_reduce_add(a4); a5 = row_reduce_add(a5);
  if (r == 0) {
    float o0 = (a0 / d0 + a2 / d1 + a4 / d2) * (1.f / 3.f) + bias2[0];
    float o1 = (a1 / d0 + a3 / d1 + a5 / d2) * (1.f / 3.f) + bias2[1];
    *(float2*)(out + (size_t)n * 2) = make_float2(o0, o1);
  }
}

// ---------------------------------------------------------------------------
extern "C" void kernel_launch(void* const* d_in, const int* in_sizes, int n_in,
                              void* d_out, int out_size, void* d_ws, size_t ws_size,
                              hipStream_t stream) {
  const float* x        = (const float*)d_in[0];
  const int*   ei       = (const int*)d_in[1];
  const float* W1       = (const float*)d_in[2];
  const float* att_src1 = (const float*)d_in[3];
  const float* att_dst1 = (const float*)d_in[4];
  const float* bias1    = (const float*)d_in[5];
  const float* W2       = (const float*)d_in[6];
  const float* att_src2 = (const float*)d_in[7];
  const float* att_dst2 = (const float*)d_in[8];
  const float* bias2    = (const float*)d_in[9];
  float* out = (float*)d_out;

  char* w = (char*)d_ws;
  auto alloc = [&](size_t bytes) {
    char* p = w;
    w += (bytes + 255) & ~(size_t)255;
    return p;
  };
  unsigned short* h1u    = (unsigned short*)alloc((size_t)N_NODES * C_HID * 2);  // 12.8 MB
  unsigned short* Wswz   = (unsigned short*)alloc((size_t)C_IN * C_HID * 2 * 2); // 256 KB
  float*          v1s    = (float*)alloc((size_t)C_IN * 4);
  float*          v1d    = (float*)alloc((size_t)C_IN * 4);
  float*          a_src1 = (float*)alloc((size_t)N_NODES * 4);
  float*          a_dst1 = (float*)alloc((size_t)N_NODES * 4);
  int*            deg    = (int*)alloc((size_t)N_NODES * 4);
  int*            rowptr = (int*)alloc((size_t)(N_NODES + 4) * 4);
  int*            rnk    = (int*)alloc((size_t)N_EDGES * 4);                     // 3.2 MB
  int2*           esw    = (int2*)alloc((size_t)E_TOT * 8);                      // 6.8 MB
  float*          hs2    = (float*)alloc((size_t)N_NODES * 12 * 4);              // 2.4 MB

  (void)hipMemsetAsync(deg, 0, (size_t)N_NODES * 4, stream);

  setup_kernel<<<160 + (N_EDGES + 255) / 256, 256, 0, stream>>>(
      W1, att_src1, att_dst1, ei, Wswz, v1s, v1d, deg, rnk);
  // scan folded into lin1's block 0 (runs concurrent with the GEMM blocks)
  lin1_kernel<<<(N_NODES + 63) / 64 + 1, 256, 0, stream>>>(x, Wswz, v1s, v1d,
                                                           h1u, a_src1, a_dst1,
                                                           deg, rowptr);
  bucket_kernel<<<(E_TOT + 255) / 256, 256, 0, stream>>>(ei, rnk, rowptr,
                                                         a_src1, a_dst1, esw);
  agg1_kernel<<<N_NODES / 16, 256, 0, stream>>>(h1u, esw, rowptr, bias1, W2,
                                                att_src2, att_dst2, hs2);
  agg2_kernel<<<(N_NODES + 15) / 16, 256, 0, stream>>>(hs2, rowptr, esw, bias2, out);
}